// Round 2
// baseline (1466.523 us; speedup 1.0000x reference)
//
#include <hip/hip_runtime.h>
#include <math.h>

#define BB 2
#define SS 2048
#define DD 768
#define NH 12
#define HH 64
#define TOK 4096  // BB*SS

// ---------------------------------------------------------------------------
// Kernel 1: per-head QKV projection + LayerNorm (q,k) fused.
// grid (TOK/16, NH, 3), block 256. which: 0=Q(ln1) 1=K(ln2) 2=V(no ln)
// Output layout: [b][n][s][h] (attention-friendly).
// ---------------------------------------------------------------------------
__global__ __launch_bounds__(256) void qkv_ln_kernel(
    const float* __restrict__ x_q, const float* __restrict__ x_kv,
    const float* __restrict__ W_Q, const float* __restrict__ W_K,
    const float* __restrict__ W_V,
    const float* __restrict__ ln1_g, const float* __restrict__ ln1_b,
    const float* __restrict__ ln2_g, const float* __restrict__ ln2_b,
    float* __restrict__ qo, float* __restrict__ ko, float* __restrict__ vo)
{
    __shared__ float xs[16 * DD];  // 48 KB
    const int tid   = threadIdx.x;
    const int which = blockIdx.z;
    const int n     = blockIdx.y;
    const int tok0  = blockIdx.x * 16;

    const float* X = (which == 0) ? x_q : x_kv;
    const float* src = X + (size_t)tok0 * DD;
    for (int i = tid; i < 16 * DD; i += 256) xs[i] = src[i];
    __syncthreads();

    const int h  = tid & 63;
    const int tg = tid >> 6;  // wave id 0..3 -> tokens tg, tg+4, tg+8, tg+12

    const float* W = (which == 0) ? W_Q : (which == 1) ? W_K : W_V;
    const float* Wp = W + (size_t)n * DD * HH + h;  // stride HH per d

    float acc0 = 0.f, acc1 = 0.f, acc2 = 0.f, acc3 = 0.f;
    #pragma unroll 4
    for (int d = 0; d < DD; ++d) {
        float w = Wp[d * HH];               // coalesced across lanes (h)
        acc0 += xs[(tg + 0)  * DD + d] * w; // LDS broadcast within wave
        acc1 += xs[(tg + 4)  * DD + d] * w;
        acc2 += xs[(tg + 8)  * DD + d] * w;
        acc3 += xs[(tg + 12) * DD + d] * w;
    }

    float* dst = (which == 0) ? qo : (which == 1) ? ko : vo;
    const bool do_ln = (which < 2);
    float g = 1.0f, bta = 0.0f;
    if (which == 0) { g = ln1_g[h]; bta = ln1_b[h]; }
    else if (which == 1) { g = ln2_g[h]; bta = ln2_b[h]; }

    float accs[4] = {acc0, acc1, acc2, acc3};
    #pragma unroll
    for (int i = 0; i < 4; ++i) {
        float v = accs[i];
        if (do_ln) {
            float s = v;
            #pragma unroll
            for (int off = 1; off < 64; off <<= 1) s += __shfl_xor(s, off);
            float mu = s * (1.0f / 64.0f);
            float dv = v - mu;
            float s2 = dv * dv;
            #pragma unroll
            for (int off = 1; off < 64; off <<= 1) s2 += __shfl_xor(s2, off);
            float var = s2 * (1.0f / 64.0f);
            v = dv * rsqrtf(var + 1e-5f) * g + bta;
        }
        const int token = tok0 + tg + 4 * i;
        const int b = token >> 11;           // token / SS
        const int s = token & (SS - 1);
        dst[(((size_t)b * NH + n) * SS + s) * HH + h] = v;
    }
}

// ---------------------------------------------------------------------------
// Kernel 2: causal flash attention, scale = 1.0.
// grid (BB*NH, SS/16), block 256 = 4 waves; wave w owns q-rows
// qbase+4w .. qbase+4w+3 (4 rows/wave, 16 rows/block).
// K/V tiles (64 rows) staged in LDS, shared by the 4 waves.
// z output layout: [b][s][n][h] (O-proj friendly).
// ---------------------------------------------------------------------------
__global__ __launch_bounds__(256) void attn_kernel(
    const float* __restrict__ q, const float* __restrict__ k,
    const float* __restrict__ v, float* __restrict__ z)
{
    __shared__ float kt[64 * 65];  // stride 65: 2-way bank aliasing (free)
    __shared__ float vt[64 * 65];
    __shared__ float qs[16 * 64];
    __shared__ float ps[16 * 64];

    const int tid  = threadIdx.x;
    const int lane = tid & 63;
    const int w    = tid >> 6;
    const int bn   = blockIdx.x;
    const int b    = bn / NH, n = bn % NH;
    const int qbase = blockIdx.y * 16;
    const int r0    = 4 * w;               // first row index (within block) of this wave

    const float* Q = q + (((size_t)b * NH + n) * SS) * HH;
    const float* K = k + (((size_t)b * NH + n) * SS) * HH;
    const float* V = v + (((size_t)b * NH + n) * SS) * HH;

    #pragma unroll
    for (int i = 0; i < 4; ++i)            // wave-local, no barrier needed
        qs[(r0 + i) * 64 + lane] = Q[(size_t)(qbase + r0 + i) * HH + lane];

    float m[4], l[4], acc[4];
    #pragma unroll
    for (int i = 0; i < 4; ++i) { m[i] = -INFINITY; l[i] = 0.f; acc[i] = 0.f; }

    const int ntiles = (qbase + 15) / 64 + 1;

    for (int t = 0; t < ntiles; ++t) {
        const int base = t * 64;
        __syncthreads();  // previous tile fully consumed
        #pragma unroll
        for (int i = 0; i < 16; ++i) {
            int idx = tid + i * 256;
            int r = idx >> 6, c = idx & 63;
            kt[r * 65 + c] = K[(size_t)(base + r) * HH + c];
            vt[r * 65 + c] = V[(size_t)(base + r) * HH + c];
        }
        __syncthreads();

        // lane j: scores(qrows r0..r0+3, base+j)
        float sc[4] = {0.f, 0.f, 0.f, 0.f};
        #pragma unroll 8
        for (int hh = 0; hh < 64; ++hh) {
            float kv = kt[lane * 65 + hh];       // reused across 4 rows
            sc[0] += qs[(r0 + 0) * 64 + hh] * kv;
            sc[1] += qs[(r0 + 1) * 64 + hh] * kv;
            sc[2] += qs[(r0 + 2) * 64 + hh] * kv;
            sc[3] += qs[(r0 + 3) * 64 + hh] * kv;
        }

        #pragma unroll
        for (int i = 0; i < 4; ++i) {
            const int qrow = qbase + r0 + i;
            const bool valid = (base + lane) <= qrow;
            float s = valid ? sc[i] : -INFINITY;
            float mt = s;
            #pragma unroll
            for (int off = 1; off < 64; off <<= 1) mt = fmaxf(mt, __shfl_xor(mt, off));
            const float mnew = fmaxf(m[i], mt);   // finite after tile 0
            const float p = valid ? __expf(s - mnew) : 0.0f;
            float psum = p;
            #pragma unroll
            for (int off = 1; off < 64; off <<= 1) psum += __shfl_xor(psum, off);
            const float scale = __expf(m[i] - mnew);  // 0 on first tile
            l[i] = l[i] * scale + psum;
            acc[i] *= scale;
            m[i] = mnew;
            ps[(r0 + i) * 64 + lane] = p;        // wave-local
        }

        #pragma unroll 4
        for (int j = 0; j < 64; ++j) {
            float vv = vt[j * 65 + lane];        // reused across 4 rows
            acc[0] += ps[(r0 + 0) * 64 + j] * vv;
            acc[1] += ps[(r0 + 1) * 64 + j] * vv;
            acc[2] += ps[(r0 + 2) * 64 + j] * vv;
            acc[3] += ps[(r0 + 3) * 64 + j] * vv;
        }
    }

    #pragma unroll
    for (int i = 0; i < 4; ++i) {
        const int qrow = qbase + r0 + i;
        z[(((size_t)b * SS + qrow) * NH + n) * HH + lane] = acc[i] / l[i];
    }
}

// ---------------------------------------------------------------------------
// Kernel 3: output projection. out[t][d] = sum_k z[t][k] * W_O[k][d]
// (W_O flat (N,H,D) == [k=n*H+h][d] already). grid (TOK/16), block 256.
// ---------------------------------------------------------------------------
__global__ __launch_bounds__(256) void oproj_kernel(
    const float* __restrict__ z, const float* __restrict__ W_O,
    float* __restrict__ out)
{
    __shared__ float zs[16 * DD];  // 48 KB
    const int tid  = threadIdx.x;
    const int tok0 = blockIdx.x * 16;

    const float* src = z + (size_t)tok0 * DD;
    for (int i = tid; i < 16 * DD; i += 256) zs[i] = src[i];
    __syncthreads();

    float acc[16][3];
    #pragma unroll
    for (int t = 0; t < 16; ++t) { acc[t][0] = acc[t][1] = acc[t][2] = 0.f; }

    for (int kk = 0; kk < DD; ++kk) {
        float w0 = W_O[(size_t)kk * DD + tid];
        float w1 = W_O[(size_t)kk * DD + tid + 256];
        float w2 = W_O[(size_t)kk * DD + tid + 512];
        #pragma unroll
        for (int t = 0; t < 16; ++t) {
            float zv = zs[t * DD + kk];  // broadcast
            acc[t][0] += zv * w0;
            acc[t][1] += zv * w1;
            acc[t][2] += zv * w2;
        }
    }

    #pragma unroll
    for (int t = 0; t < 16; ++t) {
        size_t row = (size_t)(tok0 + t) * DD;
        out[row + tid]       = acc[t][0];
        out[row + tid + 256] = acc[t][1];
        out[row + tid + 512] = acc[t][2];
    }
}

// ---------------------------------------------------------------------------
extern "C" void kernel_launch(void* const* d_in, const int* in_sizes, int n_in,
                              void* d_out, int out_size, void* d_ws, size_t ws_size,
                              hipStream_t stream) {
    const float* x_q   = (const float*)d_in[0];
    const float* x_kv  = (const float*)d_in[1];
    // d_in[2] = mask (causal, implicit — unused)
    const float* W_Q   = (const float*)d_in[3];
    const float* W_K   = (const float*)d_in[4];
    const float* W_V   = (const float*)d_in[5];
    const float* W_O   = (const float*)d_in[6];
    const float* ln1_g = (const float*)d_in[7];
    const float* ln1_b = (const float*)d_in[8];
    const float* ln2_g = (const float*)d_in[9];
    const float* ln2_b = (const float*)d_in[10];
    float* out = (float*)d_out;

    const size_t per = (size_t)BB * NH * SS * HH;  // 3,145,728 floats
    float* qw = (float*)d_ws;
    float* kw = qw + per;
    float* vw = kw + per;
    float* zw = vw + per;

    qkv_ln_kernel<<<dim3(TOK / 16, NH, 3), 256, 0, stream>>>(
        x_q, x_kv, W_Q, W_K, W_V, ln1_g, ln1_b, ln2_g, ln2_b, qw, kw, vw);
    attn_kernel<<<dim3(BB * NH, SS / 16), 256, 0, stream>>>(qw, kw, vw, zw);
    oproj_kernel<<<dim3(TOK / 16), 256, 0, stream>>>(zw, W_O, out);
}

// Round 3
// 950.480 us; speedup vs baseline: 1.5429x; 1.5429x over previous
//
#include <hip/hip_runtime.h>
#include <math.h>
#include <stdint.h>

#define BB 2
#define SS 2048
#define DD 768
#define NH 12
#define HH 64
#define TOK 4096  // BB*SS

typedef __attribute__((ext_vector_type(8))) short bf16x8;
typedef __attribute__((ext_vector_type(4))) float f32x4;

#define AS1 __attribute__((address_space(1)))
#define AS3 __attribute__((address_space(3)))

__device__ __forceinline__ void gload16(const void* g, void* l) {
    // async global->LDS, 16B per lane; LDS dest = wave-uniform base + lane*16
    __builtin_amdgcn_global_load_lds((AS1 const void*)g, (AS3 void*)l, 16, 0, 0);
}

__device__ __forceinline__ unsigned short f2bf(float f) {  // RNE
    union { float f; uint32_t u; } v; v.f = f;
    uint32_t r = v.u + 0x7fffu + ((v.u >> 16) & 1u);
    return (unsigned short)(r >> 16);
}
__device__ __forceinline__ float bf2f(unsigned short h) {
    union { uint32_t u; float f; } v; v.u = ((uint32_t)h) << 16;
    return v.f;
}

// ---------------------------------------------------------------------------
// Prep A: split-convert fp32 -> (bf16 hi, bf16 lo).  n4 = count/4.
// ---------------------------------------------------------------------------
__global__ __launch_bounds__(256) void cvt_split_kernel(
    const float* __restrict__ src, unsigned short* __restrict__ hi,
    unsigned short* __restrict__ lo, int n4)
{
    int i = blockIdx.x * 256 + threadIdx.x;
    if (i >= n4) return;
    float4 v = ((const float4*)src)[i];
    ushort4 h, l;
    h.x = f2bf(v.x); l.x = f2bf(v.x - bf2f(h.x));
    h.y = f2bf(v.y); l.y = f2bf(v.y - bf2f(h.y));
    h.z = f2bf(v.z); l.z = f2bf(v.z - bf2f(h.z));
    h.w = f2bf(v.w); l.w = f2bf(v.w - bf2f(h.w));
    ((ushort4*)hi)[i] = h;
    ((ushort4*)lo)[i] = l;
}

// ---------------------------------------------------------------------------
// Prep B: transpose one W (NH,DD,HH fp32) -> WT[n*64+h][d] as bf16 hi/lo.
// grid (NH, DD/64), block 256.
// ---------------------------------------------------------------------------
__global__ __launch_bounds__(256) void wt_kernel(
    const float* __restrict__ W, unsigned short* __restrict__ WTh,
    unsigned short* __restrict__ WTl)
{
    __shared__ float lds[64][65];
    const int n = blockIdx.x;
    const int d0 = blockIdx.y * 64;
    const int t = threadIdx.x;

    {   // coalesced read: 4 threads cover one d-row of 64 h
        const int dr = t >> 2, h0 = (t & 3) * 16;
        const float* src = W + (size_t)n * DD * HH + (size_t)(d0 + dr) * HH + h0;
        #pragma unroll
        for (int i = 0; i < 4; ++i) {
            float4 v = *(const float4*)(src + i * 4);
            lds[dr][h0 + i * 4 + 0] = v.x;
            lds[dr][h0 + i * 4 + 1] = v.y;
            lds[dr][h0 + i * 4 + 2] = v.z;
            lds[dr][h0 + i * 4 + 3] = v.w;
        }
    }
    __syncthreads();
    {   // transposed write: thread -> (h, 16 d's), 2x16B stores per array
        const int h = t >> 2, dq = (t & 3) * 16;
        unsigned short th[16], tl[16];
        #pragma unroll
        for (int i = 0; i < 16; ++i) {
            float v = lds[dq + i][h];
            th[i] = f2bf(v);
            tl[i] = f2bf(v - bf2f(th[i]));
        }
        unsigned short* dh = WTh + (size_t)(n * HH + h) * DD + d0 + dq;
        unsigned short* dl = WTl + (size_t)(n * HH + h) * DD + d0 + dq;
        *(bf16x8*)dh       = *(const bf16x8*)&th[0];
        *(bf16x8*)(dh + 8) = *(const bf16x8*)&th[8];
        *(bf16x8*)dl       = *(const bf16x8*)&tl[0];
        *(bf16x8*)(dl + 8) = *(const bf16x8*)&tl[8];
    }
}

// ---------------------------------------------------------------------------
// Kernel 1: QKV projection as MFMA GEMM + fused LayerNorm epilogue.
// C[4096 tok x 768 col] per `which` (z: 0=Q ln1, 1=K ln2, 2=V none).
// 128x128 tile, BK=64, 4 waves (2x2), 16x16x32 bf16 MFMA.
// Q,K use 3-mult bf16 split (fp32-class accuracy); V single bf16.
// Output layout: [b][n][s][h] fp32.
// ---------------------------------------------------------------------------
__global__ __launch_bounds__(256) void qkv_gemm_kernel(
    const unsigned short* __restrict__ Xqh, const unsigned short* __restrict__ Xql,
    const unsigned short* __restrict__ Xkvh, const unsigned short* __restrict__ Xkvl,
    const unsigned short* __restrict__ WTh, const unsigned short* __restrict__ WTl,
    const float* __restrict__ ln1_g, const float* __restrict__ ln1_b,
    const float* __restrict__ ln2_g, const float* __restrict__ ln2_b,
    float* __restrict__ qo, float* __restrict__ ko, float* __restrict__ vo)
{
    __shared__ unsigned short Ah_lds[128 * 64];
    __shared__ unsigned short Al_lds[128 * 64];
    __shared__ unsigned short Bh_lds[128 * 64];
    __shared__ unsigned short Bl_lds[128 * 64];

    const int tid  = threadIdx.x;
    const int lane = tid & 63;
    const int w    = tid >> 6;
    const int which = blockIdx.z;
    const int tok0 = blockIdx.x * 128;
    const int col0 = blockIdx.y * 128;

    const unsigned short* Ah = (which == 0) ? Xqh : Xkvh;
    const unsigned short* Al = (which == 0) ? Xql : Xkvl;
    const unsigned short* Bh = WTh + (size_t)which * DD * DD;  // 768x768 per which
    const unsigned short* Bl = WTl + (size_t)which * DD * DD;
    const bool split = (which < 2);

    f32x4 acc[4][4] = {};

    const int srow = lane >> 3;            // + (w*4+j)*8
    const int scol = (lane & 7) * 8;       // element offset within 64-k row

    for (int t = 0; t < 12; ++t) {
        const int kk = t * 64;
        __syncthreads();
        #pragma unroll
        for (int j = 0; j < 4; ++j) {
            const int r = (w * 4 + j) * 8 + srow;
            const int ldso = (w * 4 + j) * 512 + lane * 8;
            gload16(Ah + (size_t)(tok0 + r) * DD + kk + scol, &Ah_lds[ldso]);
            gload16(Bh + (size_t)(col0 + r) * DD + kk + scol, &Bh_lds[ldso]);
            if (split) {
                gload16(Al + (size_t)(tok0 + r) * DD + kk + scol, &Al_lds[ldso]);
                gload16(Bl + (size_t)(col0 + r) * DD + kk + scol, &Bl_lds[ldso]);
            }
        }
        __syncthreads();

        const int wm = (w >> 1) * 64, wn = (w & 1) * 64;
        #pragma unroll
        for (int kh = 0; kh < 2; ++kh) {
            const int ko = kh * 32 + (lane >> 4) * 8;
            bf16x8 ah[4], bh[4];
            #pragma unroll
            for (int m = 0; m < 4; ++m)
                ah[m] = *(const bf16x8*)&Ah_lds[(wm + m * 16 + (lane & 15)) * 64 + ko];
            #pragma unroll
            for (int n = 0; n < 4; ++n)
                bh[n] = *(const bf16x8*)&Bh_lds[(wn + n * 16 + (lane & 15)) * 64 + ko];
            #pragma unroll
            for (int m = 0; m < 4; ++m)
                #pragma unroll
                for (int n = 0; n < 4; ++n)
                    acc[m][n] = __builtin_amdgcn_mfma_f32_16x16x32_bf16(ah[m], bh[n], acc[m][n], 0, 0, 0);
            if (split) {
                bf16x8 al[4], bl[4];
                #pragma unroll
                for (int m = 0; m < 4; ++m)
                    al[m] = *(const bf16x8*)&Al_lds[(wm + m * 16 + (lane & 15)) * 64 + ko];
                #pragma unroll
                for (int n = 0; n < 4; ++n)
                    bl[n] = *(const bf16x8*)&Bl_lds[(wn + n * 16 + (lane & 15)) * 64 + ko];
                #pragma unroll
                for (int m = 0; m < 4; ++m)
                    #pragma unroll
                    for (int n = 0; n < 4; ++n) {
                        acc[m][n] = __builtin_amdgcn_mfma_f32_16x16x32_bf16(al[m], bh[n], acc[m][n], 0, 0, 0);
                        acc[m][n] = __builtin_amdgcn_mfma_f32_16x16x32_bf16(ah[m], bl[n], acc[m][n], 0, 0, 0);
                    }
            }
        }
    }

    // ---- epilogue: per-head LayerNorm (rows=tokens, wave cols = one head) ----
    const int wm = (w >> 1) * 64, wn = (w & 1);
    const int head = (col0 >> 6) + wn;
    float* dst = (which == 0) ? qo : (which == 1) ? ko : vo;
    const float* gp = (which == 0) ? ln1_g : ln2_g;
    const float* bp = (which == 0) ? ln1_b : ln2_b;

    float gq[4], bq[4];
    #pragma unroll
    for (int n = 0; n < 4; ++n) {
        const int hcol = n * 16 + (lane & 15);
        gq[n] = split ? gp[hcol] : 1.0f;
        bq[n] = split ? bp[hcol] : 0.0f;
    }

    #pragma unroll
    for (int m = 0; m < 4; ++m) {
        #pragma unroll
        for (int r = 0; r < 4; ++r) {
            float e0 = acc[m][0][r], e1 = acc[m][1][r], e2 = acc[m][2][r], e3 = acc[m][3][r];
            float v0, v1, v2, v3;
            if (split) {
                float s = e0 + e1 + e2 + e3;   // reduce over 64 head-cols:
                s += __shfl_xor(s, 1); s += __shfl_xor(s, 2);
                s += __shfl_xor(s, 4); s += __shfl_xor(s, 8);
                const float mu = s * (1.0f / 64.0f);
                float d0 = e0 - mu, d1 = e1 - mu, d2 = e2 - mu, d3 = e3 - mu;
                float ss = d0 * d0 + d1 * d1 + d2 * d2 + d3 * d3;
                ss += __shfl_xor(ss, 1); ss += __shfl_xor(ss, 2);
                ss += __shfl_xor(ss, 4); ss += __shfl_xor(ss, 8);
                const float rstd = rsqrtf(ss * (1.0f / 64.0f) + 1e-5f);
                v0 = d0 * rstd * gq[0] + bq[0];
                v1 = d1 * rstd * gq[1] + bq[1];
                v2 = d2 * rstd * gq[2] + bq[2];
                v3 = d3 * rstd * gq[3] + bq[3];
            } else { v0 = e0; v1 = e1; v2 = e2; v3 = e3; }
            const int token = tok0 + wm + m * 16 + (lane >> 4) * 4 + r;
            const int b = token >> 11, s = token & (SS - 1);
            float* o = dst + (((size_t)b * NH + head) * SS + s) * HH + (lane & 15);
            o[0] = v0; o[16] = v1; o[32] = v2; o[48] = v3;
        }
    }
}

// ---------------------------------------------------------------------------
// Kernel 2: causal flash attention, scale = 1.0 (fp32, unchanged).
// ---------------------------------------------------------------------------
__global__ __launch_bounds__(256) void attn_kernel(
    const float* __restrict__ q, const float* __restrict__ k,
    const float* __restrict__ v, float* __restrict__ z)
{
    __shared__ float kt[64 * 65];
    __shared__ float vt[64 * 65];
    __shared__ float qs[16 * 64];
    __shared__ float ps[16 * 64];

    const int tid  = threadIdx.x;
    const int lane = tid & 63;
    const int w    = tid >> 6;
    const int bn   = blockIdx.x;
    const int b    = bn / NH, n = bn % NH;
    const int qbase = blockIdx.y * 16;
    const int r0    = 4 * w;

    const float* Q = q + (((size_t)b * NH + n) * SS) * HH;
    const float* K = k + (((size_t)b * NH + n) * SS) * HH;
    const float* V = v + (((size_t)b * NH + n) * SS) * HH;

    #pragma unroll
    for (int i = 0; i < 4; ++i)
        qs[(r0 + i) * 64 + lane] = Q[(size_t)(qbase + r0 + i) * HH + lane];

    float m[4], l[4], acc[4];
    #pragma unroll
    for (int i = 0; i < 4; ++i) { m[i] = -INFINITY; l[i] = 0.f; acc[i] = 0.f; }

    const int ntiles = (qbase + 15) / 64 + 1;

    for (int t = 0; t < ntiles; ++t) {
        const int base = t * 64;
        __syncthreads();
        #pragma unroll
        for (int i = 0; i < 16; ++i) {
            int idx = tid + i * 256;
            int r = idx >> 6, c = idx & 63;
            kt[r * 65 + c] = K[(size_t)(base + r) * HH + c];
            vt[r * 65 + c] = V[(size_t)(base + r) * HH + c];
        }
        __syncthreads();

        float sc[4] = {0.f, 0.f, 0.f, 0.f};
        #pragma unroll 8
        for (int hh = 0; hh < 64; ++hh) {
            float kv = kt[lane * 65 + hh];
            sc[0] += qs[(r0 + 0) * 64 + hh] * kv;
            sc[1] += qs[(r0 + 1) * 64 + hh] * kv;
            sc[2] += qs[(r0 + 2) * 64 + hh] * kv;
            sc[3] += qs[(r0 + 3) * 64 + hh] * kv;
        }

        #pragma unroll
        for (int i = 0; i < 4; ++i) {
            const int qrow = qbase + r0 + i;
            const bool valid = (base + lane) <= qrow;
            float s = valid ? sc[i] : -INFINITY;
            float mt = s;
            #pragma unroll
            for (int off = 1; off < 64; off <<= 1) mt = fmaxf(mt, __shfl_xor(mt, off));
            const float mnew = fmaxf(m[i], mt);
            const float p = valid ? __expf(s - mnew) : 0.0f;
            float psum = p;
            #pragma unroll
            for (int off = 1; off < 64; off <<= 1) psum += __shfl_xor(psum, off);
            const float scale = __expf(m[i] - mnew);
            l[i] = l[i] * scale + psum;
            acc[i] *= scale;
            m[i] = mnew;
            ps[(r0 + i) * 64 + lane] = p;
        }

        #pragma unroll 4
        for (int j = 0; j < 64; ++j) {
            float vv = vt[j * 65 + lane];
            acc[0] += ps[(r0 + 0) * 64 + j] * vv;
            acc[1] += ps[(r0 + 1) * 64 + j] * vv;
            acc[2] += ps[(r0 + 2) * 64 + j] * vv;
            acc[3] += ps[(r0 + 3) * 64 + j] * vv;
        }
    }

    #pragma unroll
    for (int i = 0; i < 4; ++i) {
        const int qrow = qbase + r0 + i;
        z[(((size_t)b * SS + qrow) * NH + n) * HH + lane] = acc[i] / l[i];
    }
}

// ---------------------------------------------------------------------------
// Kernel 3: output projection (fp32, unchanged).
// ---------------------------------------------------------------------------
__global__ __launch_bounds__(256) void oproj_kernel(
    const float* __restrict__ z, const float* __restrict__ W_O,
    float* __restrict__ out)
{
    __shared__ float zs[16 * DD];
    const int tid  = threadIdx.x;
    const int tok0 = blockIdx.x * 16;

    const float* src = z + (size_t)tok0 * DD;
    for (int i = tid; i < 16 * DD; i += 256) zs[i] = src[i];
    __syncthreads();

    float acc[16][3];
    #pragma unroll
    for (int t = 0; t < 16; ++t) { acc[t][0] = acc[t][1] = acc[t][2] = 0.f; }

    for (int kk = 0; kk < DD; ++kk) {
        float w0 = W_O[(size_t)kk * DD + tid];
        float w1 = W_O[(size_t)kk * DD + tid + 256];
        float w2 = W_O[(size_t)kk * DD + tid + 512];
        #pragma unroll
        for (int t = 0; t < 16; ++t) {
            float zv = zs[t * DD + kk];
            acc[t][0] += zv * w0;
            acc[t][1] += zv * w1;
            acc[t][2] += zv * w2;
        }
    }

    #pragma unroll
    for (int t = 0; t < 16; ++t) {
        size_t row = (size_t)(tok0 + t) * DD;
        out[row + tid]       = acc[t][0];
        out[row + tid + 256] = acc[t][1];
        out[row + tid + 512] = acc[t][2];
    }
}

// ---------------------------------------------------------------------------
extern "C" void kernel_launch(void* const* d_in, const int* in_sizes, int n_in,
                              void* d_out, int out_size, void* d_ws, size_t ws_size,
                              hipStream_t stream) {
    const float* x_q   = (const float*)d_in[0];
    const float* x_kv  = (const float*)d_in[1];
    // d_in[2] = mask (causal, implicit — unused)
    const float* W_Q   = (const float*)d_in[3];
    const float* W_K   = (const float*)d_in[4];
    const float* W_V   = (const float*)d_in[5];
    const float* W_O   = (const float*)d_in[6];
    const float* ln1_g = (const float*)d_in[7];
    const float* ln1_b = (const float*)d_in[8];
    const float* ln2_g = (const float*)d_in[9];
    const float* ln2_b = (const float*)d_in[10];
    float* out = (float*)d_out;

    const size_t P = (size_t)BB * NH * SS * HH;   // 3,145,728 elems
    char* wsb = (char*)d_ws;
    float* qw = (float*)wsb;                       // P f32
    float* kw = qw + P;                            // P f32
    float* vw = kw + P;                            // P f32
    // X bf16 region (4*P shorts); zw (P f32) overlays its first half
    unsigned short* Xqh  = (unsigned short*)(wsb + 4 * 3 * P);
    unsigned short* Xql  = Xqh + P;
    unsigned short* Xkvh = Xql + P;
    unsigned short* Xkvl = Xkvh + P;
    float* zw = (float*)Xqh;                       // safe: attn runs after gemm
    unsigned short* WTh = (unsigned short*)(wsb + 4 * 3 * P + 2 * 4 * P);
    unsigned short* WTl = WTh + 3 * DD * DD;

    const int n4 = (int)(P / 4);
    cvt_split_kernel<<<dim3((n4 + 255) / 256), 256, 0, stream>>>(x_q, Xqh, Xql, n4);
    cvt_split_kernel<<<dim3((n4 + 255) / 256), 256, 0, stream>>>(x_kv, Xkvh, Xkvl, n4);
    wt_kernel<<<dim3(NH, DD / 64), 256, 0, stream>>>(W_Q, WTh, WTl);
    wt_kernel<<<dim3(NH, DD / 64), 256, 0, stream>>>(W_K, WTh + (size_t)DD * DD, WTl + (size_t)DD * DD);
    wt_kernel<<<dim3(NH, DD / 64), 256, 0, stream>>>(W_V, WTh + 2 * (size_t)DD * DD, WTl + 2 * (size_t)DD * DD);

    qkv_gemm_kernel<<<dim3(TOK / 128, DD / 128, 3), 256, 0, stream>>>(
        Xqh, Xql, Xkvh, Xkvl, WTh, WTl, ln1_g, ln1_b, ln2_g, ln2_b, qw, kw, vw);

    attn_kernel<<<dim3(BB * NH, SS / 16), 256, 0, stream>>>(qw, kw, vw, zw);
    oproj_kernel<<<dim3(TOK / 16), 256, 0, stream>>>(zw, W_O, out);
}

// Round 6
// 419.664 us; speedup vs baseline: 3.4945x; 2.2649x over previous
//
#include <hip/hip_runtime.h>
#include <math.h>
#include <stdint.h>

#define BB 2
#define SS 2048
#define DD 768
#define NH 12
#define HH 64
#define TOK 4096  // BB*SS

typedef __attribute__((ext_vector_type(8))) short bf16x8;
typedef __attribute__((ext_vector_type(4))) float f32x4;

#define AS1 __attribute__((address_space(1)))
#define AS3 __attribute__((address_space(3)))

__device__ __forceinline__ void gload16(const void* g, void* l) {
    __builtin_amdgcn_global_load_lds((AS1 const void*)g, (AS3 void*)l, 16, 0, 0);
}

__device__ __forceinline__ unsigned short f2bf(float f) {  // RNE
    union { float f; uint32_t u; } v; v.f = f;
    uint32_t r = v.u + 0x7fffu + ((v.u >> 16) & 1u);
    return (unsigned short)(r >> 16);
}
__device__ __forceinline__ float bf2f(unsigned short h) {
    union { uint32_t u; float f; } v; v.u = ((uint32_t)h) << 16;
    return v.f;
}
__device__ __forceinline__ bf16x8 cvt8(float4 a, float4 b) {
    unsigned short u[8] = {f2bf(a.x), f2bf(a.y), f2bf(a.z), f2bf(a.w),
                           f2bf(b.x), f2bf(b.y), f2bf(b.z), f2bf(b.w)};
    return *(const bf16x8*)u;
}

// ---------------------------------------------------------------------------
// Prep A: split-convert fp32 -> (bf16 hi, bf16 lo).  n4 = count/4.
// ---------------------------------------------------------------------------
__global__ __launch_bounds__(256) void cvt_split_kernel(
    const float* __restrict__ src, unsigned short* __restrict__ hi,
    unsigned short* __restrict__ lo, int n4)
{
    int i = blockIdx.x * 256 + threadIdx.x;
    if (i >= n4) return;
    float4 v = ((const float4*)src)[i];
    ushort4 h, l;
    h.x = f2bf(v.x); l.x = f2bf(v.x - bf2f(h.x));
    h.y = f2bf(v.y); l.y = f2bf(v.y - bf2f(h.y));
    h.z = f2bf(v.z); l.z = f2bf(v.z - bf2f(h.z));
    h.w = f2bf(v.w); l.w = f2bf(v.w - bf2f(h.w));
    ((ushort4*)hi)[i] = h;
    ((ushort4*)lo)[i] = l;
}

// ---------------------------------------------------------------------------
// Prep B: transpose one W (NH,DD,HH fp32) -> WT[n*64+h][d] as bf16 hi/lo.
// ---------------------------------------------------------------------------
__global__ __launch_bounds__(256) void wt_kernel(
    const float* __restrict__ W, unsigned short* __restrict__ WTh,
    unsigned short* __restrict__ WTl)
{
    __shared__ float lds[64][65];
    const int n = blockIdx.x;
    const int d0 = blockIdx.y * 64;
    const int t = threadIdx.x;

    {
        const int dr = t >> 2, h0 = (t & 3) * 16;
        const float* src = W + (size_t)n * DD * HH + (size_t)(d0 + dr) * HH + h0;
        #pragma unroll
        for (int i = 0; i < 4; ++i) {
            float4 v = *(const float4*)(src + i * 4);
            lds[dr][h0 + i * 4 + 0] = v.x;
            lds[dr][h0 + i * 4 + 1] = v.y;
            lds[dr][h0 + i * 4 + 2] = v.z;
            lds[dr][h0 + i * 4 + 3] = v.w;
        }
    }
    __syncthreads();
    {
        const int h = t >> 2, dq = (t & 3) * 16;
        unsigned short th[16], tl[16];
        #pragma unroll
        for (int i = 0; i < 16; ++i) {
            float v = lds[dq + i][h];
            th[i] = f2bf(v);
            tl[i] = f2bf(v - bf2f(th[i]));
        }
        unsigned short* dh = WTh + (size_t)(n * HH + h) * DD + d0 + dq;
        unsigned short* dl = WTl + (size_t)(n * HH + h) * DD + d0 + dq;
        *(bf16x8*)dh       = *(const bf16x8*)&th[0];
        *(bf16x8*)(dh + 8) = *(const bf16x8*)&th[8];
        *(bf16x8*)dl       = *(const bf16x8*)&tl[0];
        *(bf16x8*)(dl + 8) = *(const bf16x8*)&tl[8];
    }
}

// ---------------------------------------------------------------------------
// Kernel 1: QKV projection MFMA GEMM + fused LayerNorm (unchanged, passing).
// ---------------------------------------------------------------------------
__global__ __launch_bounds__(256) void qkv_gemm_kernel(
    const unsigned short* __restrict__ Xqh, const unsigned short* __restrict__ Xql,
    const unsigned short* __restrict__ Xkvh, const unsigned short* __restrict__ Xkvl,
    const unsigned short* __restrict__ WTh, const unsigned short* __restrict__ WTl,
    const float* __restrict__ ln1_g, const float* __restrict__ ln1_b,
    const float* __restrict__ ln2_g, const float* __restrict__ ln2_b,
    float* __restrict__ qo, float* __restrict__ ko, float* __restrict__ vo)
{
    __shared__ unsigned short Ah_lds[128 * 64];
    __shared__ unsigned short Al_lds[128 * 64];
    __shared__ unsigned short Bh_lds[128 * 64];
    __shared__ unsigned short Bl_lds[128 * 64];

    const int tid  = threadIdx.x;
    const int lane = tid & 63;
    const int w    = tid >> 6;
    const int which = blockIdx.z;
    const int tok0 = blockIdx.x * 128;
    const int col0 = blockIdx.y * 128;

    const unsigned short* Ah = (which == 0) ? Xqh : Xkvh;
    const unsigned short* Al = (which == 0) ? Xql : Xkvl;
    const unsigned short* Bh = WTh + (size_t)which * DD * DD;
    const unsigned short* Bl = WTl + (size_t)which * DD * DD;
    const bool split = (which < 2);

    f32x4 acc[4][4] = {};

    const int srow = lane >> 3;
    const int scol = (lane & 7) * 8;

    for (int t = 0; t < 12; ++t) {
        const int kk = t * 64;
        __syncthreads();
        #pragma unroll
        for (int j = 0; j < 4; ++j) {
            const int r = (w * 4 + j) * 8 + srow;
            const int ldso = (w * 4 + j) * 512 + lane * 8;
            gload16(Ah + (size_t)(tok0 + r) * DD + kk + scol, &Ah_lds[ldso]);
            gload16(Bh + (size_t)(col0 + r) * DD + kk + scol, &Bh_lds[ldso]);
            if (split) {
                gload16(Al + (size_t)(tok0 + r) * DD + kk + scol, &Al_lds[ldso]);
                gload16(Bl + (size_t)(col0 + r) * DD + kk + scol, &Bl_lds[ldso]);
            }
        }
        __syncthreads();

        const int wm = (w >> 1) * 64, wn = (w & 1) * 64;
        #pragma unroll
        for (int kh = 0; kh < 2; ++kh) {
            const int ko = kh * 32 + (lane >> 4) * 8;
            bf16x8 ah[4], bh[4];
            #pragma unroll
            for (int m = 0; m < 4; ++m)
                ah[m] = *(const bf16x8*)&Ah_lds[(wm + m * 16 + (lane & 15)) * 64 + ko];
            #pragma unroll
            for (int n = 0; n < 4; ++n)
                bh[n] = *(const bf16x8*)&Bh_lds[(wn + n * 16 + (lane & 15)) * 64 + ko];
            #pragma unroll
            for (int m = 0; m < 4; ++m)
                #pragma unroll
                for (int n = 0; n < 4; ++n)
                    acc[m][n] = __builtin_amdgcn_mfma_f32_16x16x32_bf16(ah[m], bh[n], acc[m][n], 0, 0, 0);
            if (split) {
                bf16x8 al[4], bl[4];
                #pragma unroll
                for (int m = 0; m < 4; ++m)
                    al[m] = *(const bf16x8*)&Al_lds[(wm + m * 16 + (lane & 15)) * 64 + ko];
                #pragma unroll
                for (int n = 0; n < 4; ++n)
                    bl[n] = *(const bf16x8*)&Bl_lds[(wn + n * 16 + (lane & 15)) * 64 + ko];
                #pragma unroll
                for (int m = 0; m < 4; ++m)
                    #pragma unroll
                    for (int n = 0; n < 4; ++n) {
                        acc[m][n] = __builtin_amdgcn_mfma_f32_16x16x32_bf16(al[m], bh[n], acc[m][n], 0, 0, 0);
                        acc[m][n] = __builtin_amdgcn_mfma_f32_16x16x32_bf16(ah[m], bl[n], acc[m][n], 0, 0, 0);
                    }
            }
        }
    }

    const int wm = (w >> 1) * 64, wn = (w & 1);
    const int head = (col0 >> 6) + wn;
    float* dst = (which == 0) ? qo : (which == 1) ? ko : vo;
    const float* gp = (which == 0) ? ln1_g : ln2_g;
    const float* bp = (which == 0) ? ln1_b : ln2_b;

    float gq[4], bq[4];
    #pragma unroll
    for (int n = 0; n < 4; ++n) {
        const int hcol = n * 16 + (lane & 15);
        gq[n] = split ? gp[hcol] : 1.0f;
        bq[n] = split ? bp[hcol] : 0.0f;
    }

    #pragma unroll
    for (int m = 0; m < 4; ++m) {
        #pragma unroll
        for (int r = 0; r < 4; ++r) {
            float e0 = acc[m][0][r], e1 = acc[m][1][r], e2 = acc[m][2][r], e3 = acc[m][3][r];
            float v0, v1, v2, v3;
            if (split) {
                float s = e0 + e1 + e2 + e3;
                s += __shfl_xor(s, 1); s += __shfl_xor(s, 2);
                s += __shfl_xor(s, 4); s += __shfl_xor(s, 8);
                const float mu = s * (1.0f / 64.0f);
                float d0 = e0 - mu, d1 = e1 - mu, d2 = e2 - mu, d3 = e3 - mu;
                float ss = d0 * d0 + d1 * d1 + d2 * d2 + d3 * d3;
                ss += __shfl_xor(ss, 1); ss += __shfl_xor(ss, 2);
                ss += __shfl_xor(ss, 4); ss += __shfl_xor(ss, 8);
                const float rstd = rsqrtf(ss * (1.0f / 64.0f) + 1e-5f);
                v0 = d0 * rstd * gq[0] + bq[0];
                v1 = d1 * rstd * gq[1] + bq[1];
                v2 = d2 * rstd * gq[2] + bq[2];
                v3 = d3 * rstd * gq[3] + bq[3];
            } else { v0 = e0; v1 = e1; v2 = e2; v3 = e3; }
            const int token = tok0 + wm + m * 16 + (lane >> 4) * 4 + r;
            const int b = token >> 11, s = token & (SS - 1);
            float* o = dst + (((size_t)b * NH + head) * SS + s) * HH + (lane & 15);
            o[0] = v0; o[16] = v1; o[32] = v2; o[48] = v3;
        }
    }
}

// ---------------------------------------------------------------------------
// Prep C: V transpose, fp32 [b][n][s][h] -> bf16 [b][n][h][s].
// grid (BB*NH, SS/64), block 256.
// ---------------------------------------------------------------------------
__global__ __launch_bounds__(256) void vtrans_kernel(
    const float* __restrict__ v, unsigned short* __restrict__ vt)
{
    __shared__ float lds[64][65];
    const int bn = blockIdx.x;
    const int s0 = blockIdx.y * 64;
    const int t  = threadIdx.x;

    const float* src = v + ((size_t)bn * SS + s0) * HH;
    {
        const int r = t >> 2, c0 = (t & 3) * 16;
        #pragma unroll
        for (int i = 0; i < 4; ++i) {
            float4 x = *(const float4*)(src + (size_t)r * HH + c0 + i * 4);
            lds[r][c0 + i * 4 + 0] = x.x;
            lds[r][c0 + i * 4 + 1] = x.y;
            lds[r][c0 + i * 4 + 2] = x.z;
            lds[r][c0 + i * 4 + 3] = x.w;
        }
    }
    __syncthreads();
    {
        const int h = t >> 2, k0 = (t & 3) * 16;
        unsigned short u[16];
        #pragma unroll
        for (int i = 0; i < 16; ++i) u[i] = f2bf(lds[k0 + i][h]);
        unsigned short* dst = vt + ((size_t)bn * HH + h) * SS + s0 + k0;
        *(bf16x8*)dst       = *(const bf16x8*)&u[0];
        *(bf16x8*)(dst + 8) = *(const bf16x8*)&u[8];
    }
}

// ---------------------------------------------------------------------------
// Kernel 2: causal flash attention with bf16 MFMA.
// grid (BB*NH, SS/64), block 256 = 4 waves; wave w owns q-rows
// qbase + w*16 .. +15. KV tiles of 64 staged to swizzled LDS.
// z output: [b][s][n][h] fp32.
// ---------------------------------------------------------------------------
__global__ __launch_bounds__(256) void attn_mfma_kernel(
    const float* __restrict__ q, const float* __restrict__ k,
    const unsigned short* __restrict__ vt, float* __restrict__ z)
{
    __shared__ unsigned short Kt[64 * 64];   // XOR-swizzled: elem ^ ((row&7)<<3)
    __shared__ unsigned short Vt[64 * 64];   // same swizzle
    __shared__ unsigned short Pt[4][16 * 64];// per-wave P tile, same swizzle

    const int tid  = threadIdx.x;
    const int lane = tid & 63;
    const int w    = tid >> 6;
    const int bn   = blockIdx.x;
    const int b    = bn / NH, n = bn % NH;
    // launch heavy (high-qbase) blocks first: reverse y
    const int qbase = (int)(gridDim.y - 1 - blockIdx.y) * 64;

    const float* Q = q + (((size_t)b * NH + n) * SS) * HH;
    const float* K = k + (((size_t)b * NH + n) * SS) * HH;
    const unsigned short* V = vt + (((size_t)b * NH + n) * HH) * SS;

    // Hoist Q A-fragments: row = lane&15 (of wave's 16), k = kh*32+(lane>>4)*8
    bf16x8 aq[2];
    {
        const int qr = qbase + w * 16 + (lane & 15);
        #pragma unroll
        for (int kh = 0; kh < 2; ++kh) {
            const float* src = Q + (size_t)qr * HH + kh * 32 + (lane >> 4) * 8;
            aq[kh] = cvt8(*(const float4*)src, *(const float4*)(src + 4));
        }
    }

    float m[4], l[4];
    f32x4 zacc[4] = {};
    #pragma unroll
    for (int r = 0; r < 4; ++r) { m[r] = -INFINITY; l[r] = 0.f; }

    const int rq = (lane >> 4) * 4;          // base row (0..12) within 16-row tile
    const int ntiles = qbase / 64 + 1;

    for (int t = 0; t < ntiles; ++t) {
        const int kv0 = t * 64;
        const bool diag = (t == ntiles - 1);

        __syncthreads();   // previous tile fully consumed
        {   // stage K (fp32->bf16) and Vt (bf16 copy), swizzled
            const int chunk = tid & 7;
            #pragma unroll
            for (int i = 0; i < 2; ++i) {
                const int row = (tid >> 3) + i * 32;
                const int idx = (row * 64 + chunk * 8) ^ ((row & 7) << 3);
                const float* ks = K + (size_t)(kv0 + row) * HH + chunk * 8;
                *(bf16x8*)&Kt[idx] = cvt8(*(const float4*)ks, *(const float4*)(ks + 4));
                const unsigned short* vs = V + (size_t)row * SS + kv0 + chunk * 8;
                *(bf16x8*)&Vt[idx] = *(const bf16x8*)vs;
            }
        }
        __syncthreads();

        // ---- QK^T: S[16 q x 64 kv] per wave ----
        f32x4 sc[4] = {};
        #pragma unroll
        for (int kh = 0; kh < 2; ++kh) {
            #pragma unroll
            for (int nt = 0; nt < 4; ++nt) {
                const int row = nt * 16 + (lane & 15);
                const int idx = (row * 64 + kh * 32 + (lane >> 4) * 8) ^ ((row & 7) << 3);
                bf16x8 kb = *(const bf16x8*)&Kt[idx];
                sc[nt] = __builtin_amdgcn_mfma_f32_16x16x32_bf16(aq[kh], kb, sc[nt], 0, 0, 0);
            }
        }

        // ---- online softmax (4 q-rows per lane; cols across 16-lane group) ----
        #pragma unroll
        for (int r = 0; r < 4; ++r) {
            float s0 = sc[0][r], s1 = sc[1][r], s2 = sc[2][r], s3 = sc[3][r];
            if (diag) {
                const int qrow = qbase + w * 16 + rq + r;
                const int kvl  = kv0 + (lane & 15);
                s0 = (kvl      <= qrow) ? s0 : -INFINITY;
                s1 = (kvl + 16 <= qrow) ? s1 : -INFINITY;
                s2 = (kvl + 32 <= qrow) ? s2 : -INFINITY;
                s3 = (kvl + 48 <= qrow) ? s3 : -INFINITY;
            }
            float mt = fmaxf(fmaxf(s0, s1), fmaxf(s2, s3));
            mt = fmaxf(mt, __shfl_xor(mt, 1));
            mt = fmaxf(mt, __shfl_xor(mt, 2));
            mt = fmaxf(mt, __shfl_xor(mt, 4));
            mt = fmaxf(mt, __shfl_xor(mt, 8));
            const float mn = fmaxf(m[r], mt);
            const float p0 = __expf(s0 - mn), p1 = __expf(s1 - mn);
            const float p2 = __expf(s2 - mn), p3 = __expf(s3 - mn);
            float ps = p0 + p1 + p2 + p3;
            ps += __shfl_xor(ps, 1);
            ps += __shfl_xor(ps, 2);
            ps += __shfl_xor(ps, 4);
            ps += __shfl_xor(ps, 8);
            const float scl = __expf(m[r] - mn);   // 0 on first tile
            l[r] = l[r] * scl + ps;
            m[r] = mn;
            zacc[0][r] *= scl; zacc[1][r] *= scl;
            zacc[2][r] *= scl; zacc[3][r] *= scl;

            // write P (bf16) to wave-local swizzled LDS, C-layout source
            const int ql = rq + r;                 // 0..15
            const int kl = lane & 15;
            const int base = ql * 64;
            const int sw = (ql & 7) << 3;
            Pt[w][(base + kl     ) ^ sw] = f2bf(p0);
            Pt[w][(base + kl + 16) ^ sw] = f2bf(p1);
            Pt[w][(base + kl + 32) ^ sw] = f2bf(p2);
            Pt[w][(base + kl + 48) ^ sw] = f2bf(p3);
        }

        // ---- PV: z[16 q x 64 h] += P[16 q x 64 kv] * V[kv x 64 h] ----
        #pragma unroll
        for (int kh = 0; kh < 2; ++kh) {
            const int ql  = lane & 15;
            const int pidx = (ql * 64 + kh * 32 + (lane >> 4) * 8) ^ ((ql & 7) << 3);
            bf16x8 pa = *(const bf16x8*)&Pt[w][pidx];
            #pragma unroll
            for (int nt = 0; nt < 4; ++nt) {
                const int row = nt * 16 + (lane & 15);   // h index
                const int idx = (row * 64 + kh * 32 + (lane >> 4) * 8) ^ ((row & 7) << 3);
                bf16x8 vb = *(const bf16x8*)&Vt[idx];
                zacc[nt] = __builtin_amdgcn_mfma_f32_16x16x32_bf16(pa, vb, zacc[nt], 0, 0, 0);
            }
        }
    }

    // ---- epilogue ----
    #pragma unroll
    for (int r = 0; r < 4; ++r) {
        const int qrow = qbase + w * 16 + rq + r;
        const float invl = 1.0f / l[r];
        float* o = z + (((size_t)b * SS + qrow) * NH + n) * HH + (lane & 15);
        o[0]  = zacc[0][r] * invl;
        o[16] = zacc[1][r] * invl;
        o[32] = zacc[2][r] * invl;
        o[48] = zacc[3][r] * invl;
    }
}

// ---------------------------------------------------------------------------
// Kernel 3: output projection (fp32, unchanged).
// ---------------------------------------------------------------------------
__global__ __launch_bounds__(256) void oproj_kernel(
    const float* __restrict__ z, const float* __restrict__ W_O,
    float* __restrict__ out)
{
    __shared__ float zs[16 * DD];
    const int tid  = threadIdx.x;
    const int tok0 = blockIdx.x * 16;

    const float* src = z + (size_t)tok0 * DD;
    for (int i = tid; i < 16 * DD; i += 256) zs[i] = src[i];
    __syncthreads();

    float acc[16][3];
    #pragma unroll
    for (int t = 0; t < 16; ++t) { acc[t][0] = acc[t][1] = acc[t][2] = 0.f; }

    for (int kk = 0; kk < DD; ++kk) {
        float w0 = W_O[(size_t)kk * DD + tid];
        float w1 = W_O[(size_t)kk * DD + tid + 256];
        float w2 = W_O[(size_t)kk * DD + tid + 512];
        #pragma unroll
        for (int t = 0; t < 16; ++t) {
            float zv = zs[t * DD + kk];
            acc[t][0] += zv * w0;
            acc[t][1] += zv * w1;
            acc[t][2] += zv * w2;
        }
    }

    #pragma unroll
    for (int t = 0; t < 16; ++t) {
        size_t row = (size_t)(tok0 + t) * DD;
        out[row + tid]       = acc[t][0];
        out[row + tid + 256] = acc[t][1];
        out[row + tid + 512] = acc[t][2];
    }
}

// ---------------------------------------------------------------------------
extern "C" void kernel_launch(void* const* d_in, const int* in_sizes, int n_in,
                              void* d_out, int out_size, void* d_ws, size_t ws_size,
                              hipStream_t stream) {
    const float* x_q   = (const float*)d_in[0];
    const float* x_kv  = (const float*)d_in[1];
    // d_in[2] = mask (causal, implicit — unused)
    const float* W_Q   = (const float*)d_in[3];
    const float* W_K   = (const float*)d_in[4];
    const float* W_V   = (const float*)d_in[5];
    const float* W_O   = (const float*)d_in[6];
    const float* ln1_g = (const float*)d_in[7];
    const float* ln1_b = (const float*)d_in[8];
    const float* ln2_g = (const float*)d_in[9];
    const float* ln2_b = (const float*)d_in[10];
    float* out = (float*)d_out;

    const size_t P = (size_t)BB * NH * SS * HH;   // 3,145,728 elems
    char* wsb = (char*)d_ws;
    float* qw = (float*)wsb;                       // P f32
    float* kw = qw + P;                            // P f32
    float* vw = kw + P;                            // P f32
    unsigned short* Xqh  = (unsigned short*)(wsb + 4 * 3 * P);
    unsigned short* Xql  = Xqh + P;
    unsigned short* Xkvh = Xql + P;
    unsigned short* Xkvl = Xkvh + P;
    float* zw = (float*)Xqh;                       // overlays Xqh+Xql (dead after gemm)
    unsigned short* vtw = Xkvh;                    // overlays Xkvh (dead after gemm)
    unsigned short* WTh = (unsigned short*)(wsb + 4 * 3 * P + 2 * 4 * P);
    unsigned short* WTl = WTh + 3 * (size_t)DD * DD;

    const int n4 = (int)(P / 4);
    cvt_split_kernel<<<dim3((n4 + 255) / 256), 256, 0, stream>>>(x_q, Xqh, Xql, n4);
    cvt_split_kernel<<<dim3((n4 + 255) / 256), 256, 0, stream>>>(x_kv, Xkvh, Xkvl, n4);
    wt_kernel<<<dim3(NH, DD / 64), 256, 0, stream>>>(W_Q, WTh, WTl);
    wt_kernel<<<dim3(NH, DD / 64), 256, 0, stream>>>(W_K, WTh + (size_t)DD * DD, WTl + (size_t)DD * DD);
    wt_kernel<<<dim3(NH, DD / 64), 256, 0, stream>>>(W_V, WTh + 2 * (size_t)DD * DD, WTl + 2 * (size_t)DD * DD);

    qkv_gemm_kernel<<<dim3(TOK / 128, DD / 128, 3), 256, 0, stream>>>(
        Xqh, Xql, Xkvh, Xkvl, WTh, WTl, ln1_g, ln1_b, ln2_g, ln2_b, qw, kw, vw);

    vtrans_kernel<<<dim3(BB * NH, SS / 64), 256, 0, stream>>>(vw, vtw);

    attn_mfma_kernel<<<dim3(BB * NH, SS / 64), 256, 0, stream>>>(qw, kw, vtw, zw);

    oproj_kernel<<<dim3(TOK / 16), 256, 0, stream>>>(zw, W_O, out);
}

// Round 7
// 295.718 us; speedup vs baseline: 4.9592x; 1.4191x over previous
//
#include <hip/hip_runtime.h>
#include <math.h>
#include <stdint.h>

#define BB 2
#define SS 2048
#define DD 768
#define NH 12
#define HH 64
#define TOK 4096  // BB*SS

typedef __attribute__((ext_vector_type(8))) short bf16x8;
typedef __attribute__((ext_vector_type(4))) float f32x4;

#define AS1 __attribute__((address_space(1)))
#define AS3 __attribute__((address_space(3)))

__device__ __forceinline__ void gload16(const void* g, void* l) {
    __builtin_amdgcn_global_load_lds((AS1 const void*)g, (AS3 void*)l, 16, 0, 0);
}

__device__ __forceinline__ unsigned short f2bf(float f) {  // RNE
    union { float f; uint32_t u; } v; v.f = f;
    uint32_t r = v.u + 0x7fffu + ((v.u >> 16) & 1u);
    return (unsigned short)(r >> 16);
}
__device__ __forceinline__ float bf2f(unsigned short h) {
    union { uint32_t u; float f; } v; v.u = ((uint32_t)h) << 16;
    return v.f;
}
__device__ __forceinline__ bf16x8 cvt8(float4 a, float4 b) {
    unsigned short u[8] = {f2bf(a.x), f2bf(a.y), f2bf(a.z), f2bf(a.w),
                           f2bf(b.x), f2bf(b.y), f2bf(b.z), f2bf(b.w)};
    return *(const bf16x8*)u;
}

// ---------------------------------------------------------------------------
// Prep A: split-convert fp32 -> (bf16 hi, bf16 lo).  n4 = count/4.
// ---------------------------------------------------------------------------
__global__ __launch_bounds__(256) void cvt_split_kernel(
    const float* __restrict__ src, unsigned short* __restrict__ hi,
    unsigned short* __restrict__ lo, int n4)
{
    int i = blockIdx.x * 256 + threadIdx.x;
    if (i >= n4) return;
    float4 v = ((const float4*)src)[i];
    ushort4 h, l;
    h.x = f2bf(v.x); l.x = f2bf(v.x - bf2f(h.x));
    h.y = f2bf(v.y); l.y = f2bf(v.y - bf2f(h.y));
    h.z = f2bf(v.z); l.z = f2bf(v.z - bf2f(h.z));
    h.w = f2bf(v.w); l.w = f2bf(v.w - bf2f(h.w));
    ((ushort4*)hi)[i] = h;
    ((ushort4*)lo)[i] = l;
}

// ---------------------------------------------------------------------------
// Prep B: transpose one W (NH,DD,HH fp32) -> WT[n*64+h][d] as bf16 hi/lo.
// ---------------------------------------------------------------------------
__global__ __launch_bounds__(256) void wt_kernel(
    const float* __restrict__ W, unsigned short* __restrict__ WTh,
    unsigned short* __restrict__ WTl)
{
    __shared__ float lds[64][65];
    const int n = blockIdx.x;
    const int d0 = blockIdx.y * 64;
    const int t = threadIdx.x;

    {
        const int dr = t >> 2, h0 = (t & 3) * 16;
        const float* src = W + (size_t)n * DD * HH + (size_t)(d0 + dr) * HH + h0;
        #pragma unroll
        for (int i = 0; i < 4; ++i) {
            float4 v = *(const float4*)(src + i * 4);
            lds[dr][h0 + i * 4 + 0] = v.x;
            lds[dr][h0 + i * 4 + 1] = v.y;
            lds[dr][h0 + i * 4 + 2] = v.z;
            lds[dr][h0 + i * 4 + 3] = v.w;
        }
    }
    __syncthreads();
    {
        const int h = t >> 2, dq = (t & 3) * 16;
        unsigned short th[16], tl[16];
        #pragma unroll
        for (int i = 0; i < 16; ++i) {
            float v = lds[dq + i][h];
            th[i] = f2bf(v);
            tl[i] = f2bf(v - bf2f(th[i]));
        }
        unsigned short* dh = WTh + (size_t)(n * HH + h) * DD + d0 + dq;
        unsigned short* dl = WTl + (size_t)(n * HH + h) * DD + d0 + dq;
        *(bf16x8*)dh       = *(const bf16x8*)&th[0];
        *(bf16x8*)(dh + 8) = *(const bf16x8*)&th[8];
        *(bf16x8*)dl       = *(const bf16x8*)&tl[0];
        *(bf16x8*)(dl + 8) = *(const bf16x8*)&tl[8];
    }
}

// ---------------------------------------------------------------------------
// Prep D: transpose W_O fp32 [k=768][d=768] -> [d][k] bf16 hi/lo.
// grid (DD/64, DD/64), block 256.
// ---------------------------------------------------------------------------
__global__ __launch_bounds__(256) void wot_kernel(
    const float* __restrict__ W, unsigned short* __restrict__ Th,
    unsigned short* __restrict__ Tl)
{
    __shared__ float lds[64][65];
    const int k0 = blockIdx.x * 64;
    const int d0 = blockIdx.y * 64;
    const int t = threadIdx.x;
    {
        const int kr = t >> 2, c0 = (t & 3) * 16;
        const float* src = W + (size_t)(k0 + kr) * DD + d0 + c0;
        #pragma unroll
        for (int i = 0; i < 4; ++i) {
            float4 v = *(const float4*)(src + i * 4);
            lds[kr][c0 + i * 4 + 0] = v.x;
            lds[kr][c0 + i * 4 + 1] = v.y;
            lds[kr][c0 + i * 4 + 2] = v.z;
            lds[kr][c0 + i * 4 + 3] = v.w;
        }
    }
    __syncthreads();
    {
        const int dr = t >> 2, kq = (t & 3) * 16;
        unsigned short th[16], tl[16];
        #pragma unroll
        for (int i = 0; i < 16; ++i) {
            float v = lds[kq + i][dr];
            th[i] = f2bf(v);
            tl[i] = f2bf(v - bf2f(th[i]));
        }
        unsigned short* dh = Th + (size_t)(d0 + dr) * DD + k0 + kq;
        unsigned short* dl = Tl + (size_t)(d0 + dr) * DD + k0 + kq;
        *(bf16x8*)dh       = *(const bf16x8*)&th[0];
        *(bf16x8*)(dh + 8) = *(const bf16x8*)&th[8];
        *(bf16x8*)dl       = *(const bf16x8*)&tl[0];
        *(bf16x8*)(dl + 8) = *(const bf16x8*)&tl[8];
    }
}

// ---------------------------------------------------------------------------
// Kernel 1: QKV projection MFMA GEMM + fused LayerNorm (unchanged, passing).
// ---------------------------------------------------------------------------
__global__ __launch_bounds__(256) void qkv_gemm_kernel(
    const unsigned short* __restrict__ Xqh, const unsigned short* __restrict__ Xql,
    const unsigned short* __restrict__ Xkvh, const unsigned short* __restrict__ Xkvl,
    const unsigned short* __restrict__ WTh, const unsigned short* __restrict__ WTl,
    const float* __restrict__ ln1_g, const float* __restrict__ ln1_b,
    const float* __restrict__ ln2_g, const float* __restrict__ ln2_b,
    float* __restrict__ qo, float* __restrict__ ko, float* __restrict__ vo)
{
    __shared__ unsigned short Ah_lds[128 * 64];
    __shared__ unsigned short Al_lds[128 * 64];
    __shared__ unsigned short Bh_lds[128 * 64];
    __shared__ unsigned short Bl_lds[128 * 64];

    const int tid  = threadIdx.x;
    const int lane = tid & 63;
    const int w    = tid >> 6;
    const int which = blockIdx.z;
    const int tok0 = blockIdx.x * 128;
    const int col0 = blockIdx.y * 128;

    const unsigned short* Ah = (which == 0) ? Xqh : Xkvh;
    const unsigned short* Al = (which == 0) ? Xql : Xkvl;
    const unsigned short* Bh = WTh + (size_t)which * DD * DD;
    const unsigned short* Bl = WTl + (size_t)which * DD * DD;
    const bool split = (which < 2);

    f32x4 acc[4][4] = {};

    const int srow = lane >> 3;
    const int scol = (lane & 7) * 8;

    for (int t = 0; t < 12; ++t) {
        const int kk = t * 64;
        __syncthreads();
        #pragma unroll
        for (int j = 0; j < 4; ++j) {
            const int r = (w * 4 + j) * 8 + srow;
            const int ldso = (w * 4 + j) * 512 + lane * 8;
            gload16(Ah + (size_t)(tok0 + r) * DD + kk + scol, &Ah_lds[ldso]);
            gload16(Bh + (size_t)(col0 + r) * DD + kk + scol, &Bh_lds[ldso]);
            if (split) {
                gload16(Al + (size_t)(tok0 + r) * DD + kk + scol, &Al_lds[ldso]);
                gload16(Bl + (size_t)(col0 + r) * DD + kk + scol, &Bl_lds[ldso]);
            }
        }
        __syncthreads();

        const int wm = (w >> 1) * 64, wn = (w & 1) * 64;
        #pragma unroll
        for (int kh = 0; kh < 2; ++kh) {
            const int ko = kh * 32 + (lane >> 4) * 8;
            bf16x8 ah[4], bh[4];
            #pragma unroll
            for (int m = 0; m < 4; ++m)
                ah[m] = *(const bf16x8*)&Ah_lds[(wm + m * 16 + (lane & 15)) * 64 + ko];
            #pragma unroll
            for (int n = 0; n < 4; ++n)
                bh[n] = *(const bf16x8*)&Bh_lds[(wn + n * 16 + (lane & 15)) * 64 + ko];
            #pragma unroll
            for (int m = 0; m < 4; ++m)
                #pragma unroll
                for (int n = 0; n < 4; ++n)
                    acc[m][n] = __builtin_amdgcn_mfma_f32_16x16x32_bf16(ah[m], bh[n], acc[m][n], 0, 0, 0);
            if (split) {
                bf16x8 al[4], bl[4];
                #pragma unroll
                for (int m = 0; m < 4; ++m)
                    al[m] = *(const bf16x8*)&Al_lds[(wm + m * 16 + (lane & 15)) * 64 + ko];
                #pragma unroll
                for (int n = 0; n < 4; ++n)
                    bl[n] = *(const bf16x8*)&Bl_lds[(wn + n * 16 + (lane & 15)) * 64 + ko];
                #pragma unroll
                for (int m = 0; m < 4; ++m)
                    #pragma unroll
                    for (int n = 0; n < 4; ++n) {
                        acc[m][n] = __builtin_amdgcn_mfma_f32_16x16x32_bf16(al[m], bh[n], acc[m][n], 0, 0, 0);
                        acc[m][n] = __builtin_amdgcn_mfma_f32_16x16x32_bf16(ah[m], bl[n], acc[m][n], 0, 0, 0);
                    }
            }
        }
    }

    const int wm = (w >> 1) * 64, wn = (w & 1);
    const int head = (col0 >> 6) + wn;
    float* dst = (which == 0) ? qo : (which == 1) ? ko : vo;
    const float* gp = (which == 0) ? ln1_g : ln2_g;
    const float* bp = (which == 0) ? ln1_b : ln2_b;

    float gq[4], bq[4];
    #pragma unroll
    for (int n = 0; n < 4; ++n) {
        const int hcol = n * 16 + (lane & 15);
        gq[n] = split ? gp[hcol] : 1.0f;
        bq[n] = split ? bp[hcol] : 0.0f;
    }

    #pragma unroll
    for (int m = 0; m < 4; ++m) {
        #pragma unroll
        for (int r = 0; r < 4; ++r) {
            float e0 = acc[m][0][r], e1 = acc[m][1][r], e2 = acc[m][2][r], e3 = acc[m][3][r];
            float v0, v1, v2, v3;
            if (split) {
                float s = e0 + e1 + e2 + e3;
                s += __shfl_xor(s, 1); s += __shfl_xor(s, 2);
                s += __shfl_xor(s, 4); s += __shfl_xor(s, 8);
                const float mu = s * (1.0f / 64.0f);
                float d0 = e0 - mu, d1 = e1 - mu, d2 = e2 - mu, d3 = e3 - mu;
                float ss = d0 * d0 + d1 * d1 + d2 * d2 + d3 * d3;
                ss += __shfl_xor(ss, 1); ss += __shfl_xor(ss, 2);
                ss += __shfl_xor(ss, 4); ss += __shfl_xor(ss, 8);
                const float rstd = rsqrtf(ss * (1.0f / 64.0f) + 1e-5f);
                v0 = d0 * rstd * gq[0] + bq[0];
                v1 = d1 * rstd * gq[1] + bq[1];
                v2 = d2 * rstd * gq[2] + bq[2];
                v3 = d3 * rstd * gq[3] + bq[3];
            } else { v0 = e0; v1 = e1; v2 = e2; v3 = e3; }
            const int token = tok0 + wm + m * 16 + (lane >> 4) * 4 + r;
            const int b = token >> 11, s = token & (SS - 1);
            float* o = dst + (((size_t)b * NH + head) * SS + s) * HH + (lane & 15);
            o[0] = v0; o[16] = v1; o[32] = v2; o[48] = v3;
        }
    }
}

// ---------------------------------------------------------------------------
// Prep C: V transpose, fp32 [b][n][s][h] -> bf16 [b][n][h][s].
// ---------------------------------------------------------------------------
__global__ __launch_bounds__(256) void vtrans_kernel(
    const float* __restrict__ v, unsigned short* __restrict__ vt)
{
    __shared__ float lds[64][65];
    const int bn = blockIdx.x;
    const int s0 = blockIdx.y * 64;
    const int t  = threadIdx.x;

    const float* src = v + ((size_t)bn * SS + s0) * HH;
    {
        const int r = t >> 2, c0 = (t & 3) * 16;
        #pragma unroll
        for (int i = 0; i < 4; ++i) {
            float4 x = *(const float4*)(src + (size_t)r * HH + c0 + i * 4);
            lds[r][c0 + i * 4 + 0] = x.x;
            lds[r][c0 + i * 4 + 1] = x.y;
            lds[r][c0 + i * 4 + 2] = x.z;
            lds[r][c0 + i * 4 + 3] = x.w;
        }
    }
    __syncthreads();
    {
        const int h = t >> 2, k0 = (t & 3) * 16;
        unsigned short u[16];
        #pragma unroll
        for (int i = 0; i < 16; ++i) u[i] = f2bf(lds[k0 + i][h]);
        unsigned short* dst = vt + ((size_t)bn * HH + h) * SS + s0 + k0;
        *(bf16x8*)dst       = *(const bf16x8*)&u[0];
        *(bf16x8*)(dst + 8) = *(const bf16x8*)&u[8];
    }
}

// ---------------------------------------------------------------------------
// Kernel 2: causal flash attention with bf16 MFMA (z output now bf16).
// ---------------------------------------------------------------------------
__global__ __launch_bounds__(256) void attn_mfma_kernel(
    const float* __restrict__ q, const float* __restrict__ k,
    const unsigned short* __restrict__ vt, unsigned short* __restrict__ zb)
{
    __shared__ unsigned short Kt[64 * 64];   // XOR-swizzled: elem ^ ((row&7)<<3)
    __shared__ unsigned short Vt[64 * 64];   // same swizzle
    __shared__ unsigned short Pt[4][16 * 64];// per-wave P tile, same swizzle

    const int tid  = threadIdx.x;
    const int lane = tid & 63;
    const int w    = tid >> 6;
    const int bn   = blockIdx.x;
    const int b    = bn / NH, n = bn % NH;
    const int qbase = (int)(gridDim.y - 1 - blockIdx.y) * 64;

    const float* Q = q + (((size_t)b * NH + n) * SS) * HH;
    const float* K = k + (((size_t)b * NH + n) * SS) * HH;
    const unsigned short* V = vt + (((size_t)b * NH + n) * HH) * SS;

    bf16x8 aq[2];
    {
        const int qr = qbase + w * 16 + (lane & 15);
        #pragma unroll
        for (int kh = 0; kh < 2; ++kh) {
            const float* src = Q + (size_t)qr * HH + kh * 32 + (lane >> 4) * 8;
            aq[kh] = cvt8(*(const float4*)src, *(const float4*)(src + 4));
        }
    }

    float m[4], l[4];
    f32x4 zacc[4] = {};
    #pragma unroll
    for (int r = 0; r < 4; ++r) { m[r] = -INFINITY; l[r] = 0.f; }

    const int rq = (lane >> 4) * 4;
    const int ntiles = qbase / 64 + 1;

    for (int t = 0; t < ntiles; ++t) {
        const int kv0 = t * 64;
        const bool diag = (t == ntiles - 1);

        __syncthreads();
        {
            const int chunk = tid & 7;
            #pragma unroll
            for (int i = 0; i < 2; ++i) {
                const int row = (tid >> 3) + i * 32;
                const int idx = (row * 64 + chunk * 8) ^ ((row & 7) << 3);
                const float* ks = K + (size_t)(kv0 + row) * HH + chunk * 8;
                *(bf16x8*)&Kt[idx] = cvt8(*(const float4*)ks, *(const float4*)(ks + 4));
                const unsigned short* vs = V + (size_t)row * SS + kv0 + chunk * 8;
                *(bf16x8*)&Vt[idx] = *(const bf16x8*)vs;
            }
        }
        __syncthreads();

        f32x4 sc[4] = {};
        #pragma unroll
        for (int kh = 0; kh < 2; ++kh) {
            #pragma unroll
            for (int nt = 0; nt < 4; ++nt) {
                const int row = nt * 16 + (lane & 15);
                const int idx = (row * 64 + kh * 32 + (lane >> 4) * 8) ^ ((row & 7) << 3);
                bf16x8 kb = *(const bf16x8*)&Kt[idx];
                sc[nt] = __builtin_amdgcn_mfma_f32_16x16x32_bf16(aq[kh], kb, sc[nt], 0, 0, 0);
            }
        }

        #pragma unroll
        for (int r = 0; r < 4; ++r) {
            float s0 = sc[0][r], s1 = sc[1][r], s2 = sc[2][r], s3 = sc[3][r];
            if (diag) {
                const int qrow = qbase + w * 16 + rq + r;
                const int kvl  = kv0 + (lane & 15);
                s0 = (kvl      <= qrow) ? s0 : -INFINITY;
                s1 = (kvl + 16 <= qrow) ? s1 : -INFINITY;
                s2 = (kvl + 32 <= qrow) ? s2 : -INFINITY;
                s3 = (kvl + 48 <= qrow) ? s3 : -INFINITY;
            }
            float mt = fmaxf(fmaxf(s0, s1), fmaxf(s2, s3));
            mt = fmaxf(mt, __shfl_xor(mt, 1));
            mt = fmaxf(mt, __shfl_xor(mt, 2));
            mt = fmaxf(mt, __shfl_xor(mt, 4));
            mt = fmaxf(mt, __shfl_xor(mt, 8));
            const float mn = fmaxf(m[r], mt);
            const float p0 = __expf(s0 - mn), p1 = __expf(s1 - mn);
            const float p2 = __expf(s2 - mn), p3 = __expf(s3 - mn);
            float ps = p0 + p1 + p2 + p3;
            ps += __shfl_xor(ps, 1);
            ps += __shfl_xor(ps, 2);
            ps += __shfl_xor(ps, 4);
            ps += __shfl_xor(ps, 8);
            const float scl = __expf(m[r] - mn);
            l[r] = l[r] * scl + ps;
            m[r] = mn;
            zacc[0][r] *= scl; zacc[1][r] *= scl;
            zacc[2][r] *= scl; zacc[3][r] *= scl;

            const int ql = rq + r;
            const int kl = lane & 15;
            const int base = ql * 64;
            const int sw = (ql & 7) << 3;
            Pt[w][(base + kl     ) ^ sw] = f2bf(p0);
            Pt[w][(base + kl + 16) ^ sw] = f2bf(p1);
            Pt[w][(base + kl + 32) ^ sw] = f2bf(p2);
            Pt[w][(base + kl + 48) ^ sw] = f2bf(p3);
        }

        #pragma unroll
        for (int kh = 0; kh < 2; ++kh) {
            const int ql  = lane & 15;
            const int pidx = (ql * 64 + kh * 32 + (lane >> 4) * 8) ^ ((ql & 7) << 3);
            bf16x8 pa = *(const bf16x8*)&Pt[w][pidx];
            #pragma unroll
            for (int nt = 0; nt < 4; ++nt) {
                const int row = nt * 16 + (lane & 15);
                const int idx = (row * 64 + kh * 32 + (lane >> 4) * 8) ^ ((row & 7) << 3);
                bf16x8 vb = *(const bf16x8*)&Vt[idx];
                zacc[nt] = __builtin_amdgcn_mfma_f32_16x16x32_bf16(pa, vb, zacc[nt], 0, 0, 0);
            }
        }
    }

    // ---- epilogue: write z as bf16 [tok][n*64+h] (GEMM-A-ready) ----
    #pragma unroll
    for (int r = 0; r < 4; ++r) {
        const int qrow = qbase + w * 16 + rq + r;
        const float invl = 1.0f / l[r];
        unsigned short* o = zb + (((size_t)b * SS + qrow) * NH + n) * HH + (lane & 15);
        o[0]  = f2bf(zacc[0][r] * invl);
        o[16] = f2bf(zacc[1][r] * invl);
        o[32] = f2bf(zacc[2][r] * invl);
        o[48] = f2bf(zacc[3][r] * invl);
    }
}

// ---------------------------------------------------------------------------
// Kernel 3: output projection as MFMA GEMM.
// out[4096 tok x 768 d] = Zb[tok][k] (bf16) x WOT[d][k] (bf16 hi+lo).
// 128x128 tile, BK=64, grid (32, 6).
// ---------------------------------------------------------------------------
__global__ __launch_bounds__(256) void oproj_gemm_kernel(
    const unsigned short* __restrict__ Zb,
    const unsigned short* __restrict__ WOTh, const unsigned short* __restrict__ WOTl,
    float* __restrict__ out)
{
    __shared__ unsigned short A_lds[128 * 64];
    __shared__ unsigned short Bh_lds[128 * 64];
    __shared__ unsigned short Bl_lds[128 * 64];

    const int tid  = threadIdx.x;
    const int lane = tid & 63;
    const int w    = tid >> 6;
    const int tok0 = blockIdx.x * 128;
    const int col0 = blockIdx.y * 128;

    f32x4 acc[4][4] = {};
    const int srow = lane >> 3;
    const int scol = (lane & 7) * 8;

    for (int t = 0; t < 12; ++t) {
        const int kk = t * 64;
        __syncthreads();
        #pragma unroll
        for (int j = 0; j < 4; ++j) {
            const int r = (w * 4 + j) * 8 + srow;
            const int ldso = (w * 4 + j) * 512 + lane * 8;
            gload16(Zb   + (size_t)(tok0 + r) * DD + kk + scol, &A_lds[ldso]);
            gload16(WOTh + (size_t)(col0 + r) * DD + kk + scol, &Bh_lds[ldso]);
            gload16(WOTl + (size_t)(col0 + r) * DD + kk + scol, &Bl_lds[ldso]);
        }
        __syncthreads();

        const int wm = (w >> 1) * 64, wn = (w & 1) * 64;
        #pragma unroll
        for (int kh = 0; kh < 2; ++kh) {
            const int ko = kh * 32 + (lane >> 4) * 8;
            bf16x8 a[4], bh[4], bl[4];
            #pragma unroll
            for (int m = 0; m < 4; ++m)
                a[m] = *(const bf16x8*)&A_lds[(wm + m * 16 + (lane & 15)) * 64 + ko];
            #pragma unroll
            for (int n = 0; n < 4; ++n) {
                bh[n] = *(const bf16x8*)&Bh_lds[(wn + n * 16 + (lane & 15)) * 64 + ko];
                bl[n] = *(const bf16x8*)&Bl_lds[(wn + n * 16 + (lane & 15)) * 64 + ko];
            }
            #pragma unroll
            for (int m = 0; m < 4; ++m)
                #pragma unroll
                for (int n = 0; n < 4; ++n) {
                    acc[m][n] = __builtin_amdgcn_mfma_f32_16x16x32_bf16(a[m], bh[n], acc[m][n], 0, 0, 0);
                    acc[m][n] = __builtin_amdgcn_mfma_f32_16x16x32_bf16(a[m], bl[n], acc[m][n], 0, 0, 0);
                }
        }
    }

    const int wm = (w >> 1) * 64, wn = (w & 1) * 64;
    #pragma unroll
    for (int m = 0; m < 4; ++m) {
        #pragma unroll
        for (int r = 0; r < 4; ++r) {
            const int token = tok0 + wm + m * 16 + (lane >> 4) * 4 + r;
            float* o = out + (size_t)token * DD + col0 + wn + (lane & 15);
            o[0]  = acc[m][0][r];
            o[16] = acc[m][1][r];
            o[32] = acc[m][2][r];
            o[48] = acc[m][3][r];
        }
    }
}

// ---------------------------------------------------------------------------
extern "C" void kernel_launch(void* const* d_in, const int* in_sizes, int n_in,
                              void* d_out, int out_size, void* d_ws, size_t ws_size,
                              hipStream_t stream) {
    const float* x_q   = (const float*)d_in[0];
    const float* x_kv  = (const float*)d_in[1];
    // d_in[2] = mask (causal, implicit — unused)
    const float* W_Q   = (const float*)d_in[3];
    const float* W_K   = (const float*)d_in[4];
    const float* W_V   = (const float*)d_in[5];
    const float* W_O   = (const float*)d_in[6];
    const float* ln1_g = (const float*)d_in[7];
    const float* ln1_b = (const float*)d_in[8];
    const float* ln2_g = (const float*)d_in[9];
    const float* ln2_b = (const float*)d_in[10];
    float* out = (float*)d_out;

    const size_t P = (size_t)BB * NH * SS * HH;   // 3,145,728 elems
    char* wsb = (char*)d_ws;
    float* qw = (float*)wsb;                       // P f32
    float* kw = qw + P;                            // P f32
    float* vw = kw + P;                            // P f32
    unsigned short* Xqh  = (unsigned short*)(wsb + 4 * 3 * P);
    unsigned short* Xql  = Xqh + P;
    unsigned short* Xkvh = Xql + P;
    unsigned short* Xkvl = Xkvh + P;
    unsigned short* zb  = Xqh;                     // overlays Xqh (dead after gemm)
    unsigned short* vtw = Xkvh;                    // overlays Xkvh (dead after gemm)
    unsigned short* WTh = (unsigned short*)(wsb + 4 * 3 * P + 2 * 4 * P);
    unsigned short* WTl = WTh + 3 * (size_t)DD * DD;
    unsigned short* WOTh = WTl + 3 * (size_t)DD * DD;
    unsigned short* WOTl = WOTh + (size_t)DD * DD;

    const int n4 = (int)(P / 4);
    cvt_split_kernel<<<dim3((n4 + 255) / 256), 256, 0, stream>>>(x_q, Xqh, Xql, n4);
    cvt_split_kernel<<<dim3((n4 + 255) / 256), 256, 0, stream>>>(x_kv, Xkvh, Xkvl, n4);
    wt_kernel<<<dim3(NH, DD / 64), 256, 0, stream>>>(W_Q, WTh, WTl);
    wt_kernel<<<dim3(NH, DD / 64), 256, 0, stream>>>(W_K, WTh + (size_t)DD * DD, WTl + (size_t)DD * DD);
    wt_kernel<<<dim3(NH, DD / 64), 256, 0, stream>>>(W_V, WTh + 2 * (size_t)DD * DD, WTl + 2 * (size_t)DD * DD);
    wot_kernel<<<dim3(DD / 64, DD / 64), 256, 0, stream>>>(W_O, WOTh, WOTl);

    qkv_gemm_kernel<<<dim3(TOK / 128, DD / 128, 3), 256, 0, stream>>>(
        Xqh, Xql, Xkvh, Xkvl, WTh, WTl, ln1_g, ln1_b, ln2_g, ln2_b, qw, kw, vw);

    vtrans_kernel<<<dim3(BB * NH, SS / 64), 256, 0, stream>>>(vw, vtw);

    attn_mfma_kernel<<<dim3(BB * NH, SS / 64), 256, 0, stream>>>(qw, kw, vtw, zb);

    oproj_gemm_kernel<<<dim3(TOK / 128, DD / 128), 256, 0, stream>>>(zb, WOTh, WOTl, out);
}

// Round 8
// 261.399 us; speedup vs baseline: 5.6103x; 1.1313x over previous
//
#include <hip/hip_runtime.h>
#include <math.h>
#include <stdint.h>

#define BB 2
#define SS 2048
#define DD 768
#define NH 12
#define HH 64
#define TOK 4096  // BB*SS

typedef __attribute__((ext_vector_type(8))) short bf16x8;
typedef __attribute__((ext_vector_type(4))) float f32x4;

#define AS1 __attribute__((address_space(1)))
#define AS3 __attribute__((address_space(3)))

__device__ __forceinline__ void gload16(const void* g, void* l) {
    __builtin_amdgcn_global_load_lds((AS1 const void*)g, (AS3 void*)l, 16, 0, 0);
}

__device__ __forceinline__ unsigned short f2bf(float f) {  // RNE
    union { float f; uint32_t u; } v; v.f = f;
    uint32_t r = v.u + 0x7fffu + ((v.u >> 16) & 1u);
    return (unsigned short)(r >> 16);
}
__device__ __forceinline__ float bf2f(unsigned short h) {
    union { uint32_t u; float f; } v; v.u = ((uint32_t)h) << 16;
    return v.f;
}
__device__ __forceinline__ bf16x8 cvt8(float4 a, float4 b) {
    unsigned short u[8] = {f2bf(a.x), f2bf(a.y), f2bf(a.z), f2bf(a.w),
                           f2bf(b.x), f2bf(b.y), f2bf(b.z), f2bf(b.w)};
    return *(const bf16x8*)u;
}

// ---------------------------------------------------------------------------
// Prep A: split-convert fp32 -> (bf16 hi, bf16 lo).  n4 = count/4.
// ---------------------------------------------------------------------------
__global__ __launch_bounds__(256) void cvt_split_kernel(
    const float* __restrict__ src, unsigned short* __restrict__ hi,
    unsigned short* __restrict__ lo, int n4)
{
    int i = blockIdx.x * 256 + threadIdx.x;
    if (i >= n4) return;
    float4 v = ((const float4*)src)[i];
    ushort4 h, l;
    h.x = f2bf(v.x); l.x = f2bf(v.x - bf2f(h.x));
    h.y = f2bf(v.y); l.y = f2bf(v.y - bf2f(h.y));
    h.z = f2bf(v.z); l.z = f2bf(v.z - bf2f(h.z));
    h.w = f2bf(v.w); l.w = f2bf(v.w - bf2f(h.w));
    ((ushort4*)hi)[i] = h;
    ((ushort4*)lo)[i] = l;
}

// ---------------------------------------------------------------------------
// Prep B: transpose one W (NH,DD,HH fp32) -> WT[n*64+h][d] as bf16 hi/lo.
// ---------------------------------------------------------------------------
__global__ __launch_bounds__(256) void wt_kernel(
    const float* __restrict__ W, unsigned short* __restrict__ WTh,
    unsigned short* __restrict__ WTl)
{
    __shared__ float lds[64][65];
    const int n = blockIdx.x;
    const int d0 = blockIdx.y * 64;
    const int t = threadIdx.x;

    {
        const int dr = t >> 2, h0 = (t & 3) * 16;
        const float* src = W + (size_t)n * DD * HH + (size_t)(d0 + dr) * HH + h0;
        #pragma unroll
        for (int i = 0; i < 4; ++i) {
            float4 v = *(const float4*)(src + i * 4);
            lds[dr][h0 + i * 4 + 0] = v.x;
            lds[dr][h0 + i * 4 + 1] = v.y;
            lds[dr][h0 + i * 4 + 2] = v.z;
            lds[dr][h0 + i * 4 + 3] = v.w;
        }
    }
    __syncthreads();
    {
        const int h = t >> 2, dq = (t & 3) * 16;
        unsigned short th[16], tl[16];
        #pragma unroll
        for (int i = 0; i < 16; ++i) {
            float v = lds[dq + i][h];
            th[i] = f2bf(v);
            tl[i] = f2bf(v - bf2f(th[i]));
        }
        unsigned short* dh = WTh + (size_t)(n * HH + h) * DD + d0 + dq;
        unsigned short* dl = WTl + (size_t)(n * HH + h) * DD + d0 + dq;
        *(bf16x8*)dh       = *(const bf16x8*)&th[0];
        *(bf16x8*)(dh + 8) = *(const bf16x8*)&th[8];
        *(bf16x8*)dl       = *(const bf16x8*)&tl[0];
        *(bf16x8*)(dl + 8) = *(const bf16x8*)&tl[8];
    }
}

// ---------------------------------------------------------------------------
// Prep D: transpose W_O fp32 [k=768][d=768] -> [d][k] bf16 hi/lo.
// ---------------------------------------------------------------------------
__global__ __launch_bounds__(256) void wot_kernel(
    const float* __restrict__ W, unsigned short* __restrict__ Th,
    unsigned short* __restrict__ Tl)
{
    __shared__ float lds[64][65];
    const int k0 = blockIdx.x * 64;
    const int d0 = blockIdx.y * 64;
    const int t = threadIdx.x;
    {
        const int kr = t >> 2, c0 = (t & 3) * 16;
        const float* src = W + (size_t)(k0 + kr) * DD + d0 + c0;
        #pragma unroll
        for (int i = 0; i < 4; ++i) {
            float4 v = *(const float4*)(src + i * 4);
            lds[kr][c0 + i * 4 + 0] = v.x;
            lds[kr][c0 + i * 4 + 1] = v.y;
            lds[kr][c0 + i * 4 + 2] = v.z;
            lds[kr][c0 + i * 4 + 3] = v.w;
        }
    }
    __syncthreads();
    {
        const int dr = t >> 2, kq = (t & 3) * 16;
        unsigned short th[16], tl[16];
        #pragma unroll
        for (int i = 0; i < 16; ++i) {
            float v = lds[kq + i][dr];
            th[i] = f2bf(v);
            tl[i] = f2bf(v - bf2f(th[i]));
        }
        unsigned short* dh = Th + (size_t)(d0 + dr) * DD + k0 + kq;
        unsigned short* dl = Tl + (size_t)(d0 + dr) * DD + k0 + kq;
        *(bf16x8*)dh       = *(const bf16x8*)&th[0];
        *(bf16x8*)(dh + 8) = *(const bf16x8*)&th[8];
        *(bf16x8*)dl       = *(const bf16x8*)&tl[0];
        *(bf16x8*)(dl + 8) = *(const bf16x8*)&tl[8];
    }
}

// ---------------------------------------------------------------------------
// Kernel 1: QKV projection MFMA GEMM + fused LayerNorm.
// Q,K outputs now written directly as bf16 [b][n][s][h]; V stays fp32.
// ---------------------------------------------------------------------------
__global__ __launch_bounds__(256) void qkv_gemm_kernel(
    const unsigned short* __restrict__ Xqh, const unsigned short* __restrict__ Xql,
    const unsigned short* __restrict__ Xkvh, const unsigned short* __restrict__ Xkvl,
    const unsigned short* __restrict__ WTh, const unsigned short* __restrict__ WTl,
    const float* __restrict__ ln1_g, const float* __restrict__ ln1_b,
    const float* __restrict__ ln2_g, const float* __restrict__ ln2_b,
    unsigned short* __restrict__ qo, unsigned short* __restrict__ ko,
    float* __restrict__ vo)
{
    __shared__ unsigned short Ah_lds[128 * 64];
    __shared__ unsigned short Al_lds[128 * 64];
    __shared__ unsigned short Bh_lds[128 * 64];
    __shared__ unsigned short Bl_lds[128 * 64];

    const int tid  = threadIdx.x;
    const int lane = tid & 63;
    const int w    = tid >> 6;
    const int which = blockIdx.z;
    const int tok0 = blockIdx.x * 128;
    const int col0 = blockIdx.y * 128;

    const unsigned short* Ah = (which == 0) ? Xqh : Xkvh;
    const unsigned short* Al = (which == 0) ? Xql : Xkvl;
    const unsigned short* Bh = WTh + (size_t)which * DD * DD;
    const unsigned short* Bl = WTl + (size_t)which * DD * DD;
    const bool split = (which < 2);

    f32x4 acc[4][4] = {};

    const int srow = lane >> 3;
    const int scol = (lane & 7) * 8;

    for (int t = 0; t < 12; ++t) {
        const int kk = t * 64;
        __syncthreads();
        #pragma unroll
        for (int j = 0; j < 4; ++j) {
            const int r = (w * 4 + j) * 8 + srow;
            const int ldso = (w * 4 + j) * 512 + lane * 8;
            gload16(Ah + (size_t)(tok0 + r) * DD + kk + scol, &Ah_lds[ldso]);
            gload16(Bh + (size_t)(col0 + r) * DD + kk + scol, &Bh_lds[ldso]);
            if (split) {
                gload16(Al + (size_t)(tok0 + r) * DD + kk + scol, &Al_lds[ldso]);
                gload16(Bl + (size_t)(col0 + r) * DD + kk + scol, &Bl_lds[ldso]);
            }
        }
        __syncthreads();

        const int wm = (w >> 1) * 64, wn = (w & 1) * 64;
        #pragma unroll
        for (int kh = 0; kh < 2; ++kh) {
            const int ko_ = kh * 32 + (lane >> 4) * 8;
            bf16x8 ah[4], bh[4];
            #pragma unroll
            for (int m = 0; m < 4; ++m)
                ah[m] = *(const bf16x8*)&Ah_lds[(wm + m * 16 + (lane & 15)) * 64 + ko_];
            #pragma unroll
            for (int n = 0; n < 4; ++n)
                bh[n] = *(const bf16x8*)&Bh_lds[(wn + n * 16 + (lane & 15)) * 64 + ko_];
            #pragma unroll
            for (int m = 0; m < 4; ++m)
                #pragma unroll
                for (int n = 0; n < 4; ++n)
                    acc[m][n] = __builtin_amdgcn_mfma_f32_16x16x32_bf16(ah[m], bh[n], acc[m][n], 0, 0, 0);
            if (split) {
                bf16x8 al[4], bl[4];
                #pragma unroll
                for (int m = 0; m < 4; ++m)
                    al[m] = *(const bf16x8*)&Al_lds[(wm + m * 16 + (lane & 15)) * 64 + ko_];
                #pragma unroll
                for (int n = 0; n < 4; ++n)
                    bl[n] = *(const bf16x8*)&Bl_lds[(wn + n * 16 + (lane & 15)) * 64 + ko_];
                #pragma unroll
                for (int m = 0; m < 4; ++m)
                    #pragma unroll
                    for (int n = 0; n < 4; ++n) {
                        acc[m][n] = __builtin_amdgcn_mfma_f32_16x16x32_bf16(al[m], bh[n], acc[m][n], 0, 0, 0);
                        acc[m][n] = __builtin_amdgcn_mfma_f32_16x16x32_bf16(ah[m], bl[n], acc[m][n], 0, 0, 0);
                    }
            }
        }
    }

    const int wm = (w >> 1) * 64, wn = (w & 1);
    const int head = (col0 >> 6) + wn;
    unsigned short* dst16 = (which == 0) ? qo : ko;   // used when split
    const float* gp = (which == 0) ? ln1_g : ln2_g;
    const float* bp = (which == 0) ? ln1_b : ln2_b;

    float gq[4], bq[4];
    #pragma unroll
    for (int n = 0; n < 4; ++n) {
        const int hcol = n * 16 + (lane & 15);
        gq[n] = split ? gp[hcol] : 1.0f;
        bq[n] = split ? bp[hcol] : 0.0f;
    }

    #pragma unroll
    for (int m = 0; m < 4; ++m) {
        #pragma unroll
        for (int r = 0; r < 4; ++r) {
            float e0 = acc[m][0][r], e1 = acc[m][1][r], e2 = acc[m][2][r], e3 = acc[m][3][r];
            const int token = tok0 + wm + m * 16 + (lane >> 4) * 4 + r;
            const int b = token >> 11, s = token & (SS - 1);
            const size_t off = (((size_t)b * NH + head) * SS + s) * HH + (lane & 15);
            if (split) {
                float sum = e0 + e1 + e2 + e3;
                sum += __shfl_xor(sum, 1); sum += __shfl_xor(sum, 2);
                sum += __shfl_xor(sum, 4); sum += __shfl_xor(sum, 8);
                const float mu = sum * (1.0f / 64.0f);
                float d0 = e0 - mu, d1 = e1 - mu, d2 = e2 - mu, d3 = e3 - mu;
                float ss = d0 * d0 + d1 * d1 + d2 * d2 + d3 * d3;
                ss += __shfl_xor(ss, 1); ss += __shfl_xor(ss, 2);
                ss += __shfl_xor(ss, 4); ss += __shfl_xor(ss, 8);
                const float rstd = rsqrtf(ss * (1.0f / 64.0f) + 1e-5f);
                unsigned short* o = dst16 + off;
                o[0]  = f2bf(d0 * rstd * gq[0] + bq[0]);
                o[16] = f2bf(d1 * rstd * gq[1] + bq[1]);
                o[32] = f2bf(d2 * rstd * gq[2] + bq[2]);
                o[48] = f2bf(d3 * rstd * gq[3] + bq[3]);
            } else {
                float* o = vo + off;
                o[0] = e0; o[16] = e1; o[32] = e2; o[48] = e3;
            }
        }
    }
}

// ---------------------------------------------------------------------------
// Prep C: V transpose, fp32 [b][n][s][h] -> bf16 [b][n][h][s].
// ---------------------------------------------------------------------------
__global__ __launch_bounds__(256) void vtrans_kernel(
    const float* __restrict__ v, unsigned short* __restrict__ vt)
{
    __shared__ float lds[64][65];
    const int bn = blockIdx.x;
    const int s0 = blockIdx.y * 64;
    const int t  = threadIdx.x;

    const float* src = v + ((size_t)bn * SS + s0) * HH;
    {
        const int r = t >> 2, c0 = (t & 3) * 16;
        #pragma unroll
        for (int i = 0; i < 4; ++i) {
            float4 x = *(const float4*)(src + (size_t)r * HH + c0 + i * 4);
            lds[r][c0 + i * 4 + 0] = x.x;
            lds[r][c0 + i * 4 + 1] = x.y;
            lds[r][c0 + i * 4 + 2] = x.z;
            lds[r][c0 + i * 4 + 3] = x.w;
        }
    }
    __syncthreads();
    {
        const int h = t >> 2, k0 = (t & 3) * 16;
        unsigned short u[16];
        #pragma unroll
        for (int i = 0; i < 16; ++i) u[i] = f2bf(lds[k0 + i][h]);
        unsigned short* dst = vt + ((size_t)bn * HH + h) * SS + s0 + k0;
        *(bf16x8*)dst       = *(const bf16x8*)&u[0];
        *(bf16x8*)(dst + 8) = *(const bf16x8*)&u[8];
    }
}

// ---------------------------------------------------------------------------
// Kernel 2: causal flash attention, bf16 MFMA, m97-style staging:
// global_load_lds (pre-swizzled source) + double-buffered LDS + 1 barrier/tile.
// grid (BB*NH, SS/64), block 256 = 4 waves; wave w owns q-rows qbase+w*16..+15.
// ---------------------------------------------------------------------------
__global__ __launch_bounds__(256) void attn_mfma_kernel(
    const unsigned short* __restrict__ q, const unsigned short* __restrict__ k,
    const unsigned short* __restrict__ vt, unsigned short* __restrict__ zb)
{
    __shared__ unsigned short Kt[2][64 * 64];   // LDS linear; data pre-swizzled at src
    __shared__ unsigned short Vt[2][64 * 64];
    __shared__ unsigned short Pt[4][16 * 64];   // per-wave P tile, XOR-swizzled

    const int tid  = threadIdx.x;
    const int lane = tid & 63;
    const int w    = tid >> 6;
    const int bn   = blockIdx.x;
    const int b    = bn / NH, n = bn % NH;
    const int qbase = (int)(gridDim.y - 1 - blockIdx.y) * 64;  // heavy-first

    const unsigned short* Q = q + (((size_t)b * NH + n) * SS) * HH;
    const unsigned short* K = k + (((size_t)b * NH + n) * SS) * HH;
    const unsigned short* V = vt + (((size_t)b * NH + n) * HH) * SS;

    // Q A-fragments (bf16 direct, no conversion)
    bf16x8 aq[2];
    {
        const int qr = qbase + w * 16 + (lane & 15);
        #pragma unroll
        for (int kh = 0; kh < 2; ++kh)
            aq[kh] = *(const bf16x8*)(Q + (size_t)qr * HH + kh * 32 + (lane >> 4) * 8);
    }

    float m[4], l[4];
    f32x4 zacc[4] = {};
    #pragma unroll
    for (int r = 0; r < 4; ++r) { m[r] = -INFINITY; l[r] = 0.f; }

    const int rq = (lane >> 4) * 4;
    const int ntiles = qbase / 64 + 1;

    // staging geometry: inst i covers rows i*8..i*8+7; lane -> (row = i*8+lrow,
    // chunk = lane&7). Source col pre-swizzled so LDS-linear == swizzled layout.
    const int lrow = lane >> 3;
    const int sw8  = 8 * ((lane & 7) ^ lrow);   // swizzled 8-elem column offset
    const int ldst = lane * 8;                  // LDS elem offset within inst block

    auto stage = [&](int bufi, int t_) {
        const int kv0_ = t_ * 64;
        #pragma unroll
        for (int j = 0; j < 2; ++j) {
            const int i_ = 2 * w + j;           // this wave's 2 K-insts + 2 V-insts
            const int row_ = i_ * 8 + lrow;
            gload16(K + (size_t)(kv0_ + row_) * HH + sw8, &Kt[bufi][i_ * 512 + ldst]);
            gload16(V + (size_t)row_ * SS + kv0_ + sw8,   &Vt[bufi][i_ * 512 + ldst]);
        }
    };

    stage(0, 0);

    for (int t = 0; t < ntiles; ++t) {
        const int cur = t & 1;
        const int kv0 = t * 64;
        const bool diag = (t == ntiles - 1);

        // __syncthreads drains this wave's stage(t) (implicit vmcnt(0)) and
        // guarantees every wave's stage(t) landed. stage(t+1) is issued AFTER,
        // so its loads stay in flight across the whole compute phase.
        __syncthreads();
        if (t + 1 < ntiles) stage(cur ^ 1, t + 1);

        // ---- QK^T ----
        f32x4 sc[4] = {};
        __builtin_amdgcn_s_setprio(1);
        #pragma unroll
        for (int kh = 0; kh < 2; ++kh) {
            #pragma unroll
            for (int nt = 0; nt < 4; ++nt) {
                const int row = nt * 16 + (lane & 15);
                const int idx = (row * 64 + kh * 32 + (lane >> 4) * 8) ^ ((row & 7) << 3);
                bf16x8 kb = *(const bf16x8*)&Kt[cur][idx];
                sc[nt] = __builtin_amdgcn_mfma_f32_16x16x32_bf16(aq[kh], kb, sc[nt], 0, 0, 0);
            }
        }
        __builtin_amdgcn_s_setprio(0);

        // ---- online softmax ----
        #pragma unroll
        for (int r = 0; r < 4; ++r) {
            float s0 = sc[0][r], s1 = sc[1][r], s2 = sc[2][r], s3 = sc[3][r];
            if (diag) {
                const int qrow = qbase + w * 16 + rq + r;
                const int kvl  = kv0 + (lane & 15);
                s0 = (kvl      <= qrow) ? s0 : -INFINITY;
                s1 = (kvl + 16 <= qrow) ? s1 : -INFINITY;
                s2 = (kvl + 32 <= qrow) ? s2 : -INFINITY;
                s3 = (kvl + 48 <= qrow) ? s3 : -INFINITY;
            }
            float mt = fmaxf(fmaxf(s0, s1), fmaxf(s2, s3));
            mt = fmaxf(mt, __shfl_xor(mt, 1));
            mt = fmaxf(mt, __shfl_xor(mt, 2));
            mt = fmaxf(mt, __shfl_xor(mt, 4));
            mt = fmaxf(mt, __shfl_xor(mt, 8));
            const float mn = fmaxf(m[r], mt);
            const float p0 = __expf(s0 - mn), p1 = __expf(s1 - mn);
            const float p2 = __expf(s2 - mn), p3 = __expf(s3 - mn);
            float ps = p0 + p1 + p2 + p3;
            ps += __shfl_xor(ps, 1);
            ps += __shfl_xor(ps, 2);
            ps += __shfl_xor(ps, 4);
            ps += __shfl_xor(ps, 8);
            const float scl = __expf(m[r] - mn);   // 0 on first tile
            l[r] = l[r] * scl + ps;
            m[r] = mn;
            zacc[0][r] *= scl; zacc[1][r] *= scl;
            zacc[2][r] *= scl; zacc[3][r] *= scl;

            const int ql = rq + r;
            const int kl = lane & 15;
            const int base = ql * 64;
            const int sw = (ql & 7) << 3;
            Pt[w][(base + kl     ) ^ sw] = f2bf(p0);
            Pt[w][(base + kl + 16) ^ sw] = f2bf(p1);
            Pt[w][(base + kl + 32) ^ sw] = f2bf(p2);
            Pt[w][(base + kl + 48) ^ sw] = f2bf(p3);
        }

        // ---- PV ----
        __builtin_amdgcn_s_setprio(1);
        #pragma unroll
        for (int kh = 0; kh < 2; ++kh) {
            const int ql  = lane & 15;
            const int pidx = (ql * 64 + kh * 32 + (lane >> 4) * 8) ^ ((ql & 7) << 3);
            bf16x8 pa = *(const bf16x8*)&Pt[w][pidx];
            #pragma unroll
            for (int nt = 0; nt < 4; ++nt) {
                const int row = nt * 16 + (lane & 15);
                const int idx = (row * 64 + kh * 32 + (lane >> 4) * 8) ^ ((row & 7) << 3);
                bf16x8 vb = *(const bf16x8*)&Vt[cur][idx];
                zacc[nt] = __builtin_amdgcn_mfma_f32_16x16x32_bf16(pa, vb, zacc[nt], 0, 0, 0);
            }
        }
        __builtin_amdgcn_s_setprio(0);
    }

    // ---- epilogue: z as bf16 [tok][n*64+h] ----
    #pragma unroll
    for (int r = 0; r < 4; ++r) {
        const int qrow = qbase + w * 16 + rq + r;
        const float invl = 1.0f / l[r];
        unsigned short* o = zb + (((size_t)b * SS + qrow) * NH + n) * HH + (lane & 15);
        o[0]  = f2bf(zacc[0][r] * invl);
        o[16] = f2bf(zacc[1][r] * invl);
        o[32] = f2bf(zacc[2][r] * invl);
        o[48] = f2bf(zacc[3][r] * invl);
    }
}

// ---------------------------------------------------------------------------
// Kernel 3: output projection as MFMA GEMM (unchanged, passing).
// ---------------------------------------------------------------------------
__global__ __launch_bounds__(256) void oproj_gemm_kernel(
    const unsigned short* __restrict__ Zb,
    const unsigned short* __restrict__ WOTh, const unsigned short* __restrict__ WOTl,
    float* __restrict__ out)
{
    __shared__ unsigned short A_lds[128 * 64];
    __shared__ unsigned short Bh_lds[128 * 64];
    __shared__ unsigned short Bl_lds[128 * 64];

    const int tid  = threadIdx.x;
    const int lane = tid & 63;
    const int w    = tid >> 6;
    const int tok0 = blockIdx.x * 128;
    const int col0 = blockIdx.y * 128;

    f32x4 acc[4][4] = {};
    const int srow = lane >> 3;
    const int scol = (lane & 7) * 8;

    for (int t = 0; t < 12; ++t) {
        const int kk = t * 64;
        __syncthreads();
        #pragma unroll
        for (int j = 0; j < 4; ++j) {
            const int r = (w * 4 + j) * 8 + srow;
            const int ldso = (w * 4 + j) * 512 + lane * 8;
            gload16(Zb   + (size_t)(tok0 + r) * DD + kk + scol, &A_lds[ldso]);
            gload16(WOTh + (size_t)(col0 + r) * DD + kk + scol, &Bh_lds[ldso]);
            gload16(WOTl + (size_t)(col0 + r) * DD + kk + scol, &Bl_lds[ldso]);
        }
        __syncthreads();

        const int wm = (w >> 1) * 64, wn = (w & 1) * 64;
        #pragma unroll
        for (int kh = 0; kh < 2; ++kh) {
            const int ko_ = kh * 32 + (lane >> 4) * 8;
            bf16x8 a[4], bh[4], bl[4];
            #pragma unroll
            for (int m = 0; m < 4; ++m)
                a[m] = *(const bf16x8*)&A_lds[(wm + m * 16 + (lane & 15)) * 64 + ko_];
            #pragma unroll
            for (int n = 0; n < 4; ++n) {
                bh[n] = *(const bf16x8*)&Bh_lds[(wn + n * 16 + (lane & 15)) * 64 + ko_];
                bl[n] = *(const bf16x8*)&Bl_lds[(wn + n * 16 + (lane & 15)) * 64 + ko_];
            }
            #pragma unroll
            for (int m = 0; m < 4; ++m)
                #pragma unroll
                for (int n = 0; n < 4; ++n) {
                    acc[m][n] = __builtin_amdgcn_mfma_f32_16x16x32_bf16(a[m], bh[n], acc[m][n], 0, 0, 0);
                    acc[m][n] = __builtin_amdgcn_mfma_f32_16x16x32_bf16(a[m], bl[n], acc[m][n], 0, 0, 0);
                }
        }
    }

    const int wm = (w >> 1) * 64, wn = (w & 1) * 64;
    #pragma unroll
    for (int m = 0; m < 4; ++m) {
        #pragma unroll
        for (int r = 0; r < 4; ++r) {
            const int token = tok0 + wm + m * 16 + (lane >> 4) * 4 + r;
            float* o = out + (size_t)token * DD + col0 + wn + (lane & 15);
            o[0]  = acc[m][0][r];
            o[16] = acc[m][1][r];
            o[32] = acc[m][2][r];
            o[48] = acc[m][3][r];
        }
    }
}

// ---------------------------------------------------------------------------
extern "C" void kernel_launch(void* const* d_in, const int* in_sizes, int n_in,
                              void* d_out, int out_size, void* d_ws, size_t ws_size,
                              hipStream_t stream) {
    const float* x_q   = (const float*)d_in[0];
    const float* x_kv  = (const float*)d_in[1];
    // d_in[2] = mask (causal, implicit — unused)
    const float* W_Q   = (const float*)d_in[3];
    const float* W_K   = (const float*)d_in[4];
    const float* W_V   = (const float*)d_in[5];
    const float* W_O   = (const float*)d_in[6];
    const float* ln1_g = (const float*)d_in[7];
    const float* ln1_b = (const float*)d_in[8];
    const float* ln2_g = (const float*)d_in[9];
    const float* ln2_b = (const float*)d_in[10];
    float* out = (float*)d_out;

    const size_t P = (size_t)BB * NH * SS * HH;   // 3,145,728 elems
    char* wsb = (char*)d_ws;
    // layout (bytes): qwb[0,2P) kwb[2P,4P) vw[4P,8P) zb[8P,10P) vtw[10P,12P)
    //                 X[12P,20P) WT/WOT after
    unsigned short* qwb = (unsigned short*)wsb;
    unsigned short* kwb = qwb + P;
    float*          vw  = (float*)(wsb + 4 * P);
    unsigned short* zb  = (unsigned short*)(wsb + 8 * P);
    unsigned short* vtw = (unsigned short*)(wsb + 10 * P);
    unsigned short* Xqh  = (unsigned short*)(wsb + 12 * P);
    unsigned short* Xql  = Xqh + P;
    unsigned short* Xkvh = Xql + P;
    unsigned short* Xkvl = Xkvh + P;
    unsigned short* WTh  = (unsigned short*)(wsb + 20 * P);
    unsigned short* WTl  = WTh + 3 * (size_t)DD * DD;
    unsigned short* WOTh = WTl + 3 * (size_t)DD * DD;
    unsigned short* WOTl = WOTh + (size_t)DD * DD;

    const int n4 = (int)(P / 4);
    cvt_split_kernel<<<dim3((n4 + 255) / 256), 256, 0, stream>>>(x_q, Xqh, Xql, n4);
    cvt_split_kernel<<<dim3((n4 + 255) / 256), 256, 0, stream>>>(x_kv, Xkvh, Xkvl, n4);
    wt_kernel<<<dim3(NH, DD / 64), 256, 0, stream>>>(W_Q, WTh, WTl);
    wt_kernel<<<dim3(NH, DD / 64), 256, 0, stream>>>(W_K, WTh + (size_t)DD * DD, WTl + (size_t)DD * DD);
    wt_kernel<<<dim3(NH, DD / 64), 256, 0, stream>>>(W_V, WTh + 2 * (size_t)DD * DD, WTl + 2 * (size_t)DD * DD);
    wot_kernel<<<dim3(DD / 64, DD / 64), 256, 0, stream>>>(W_O, WOTh, WOTl);

    qkv_gemm_kernel<<<dim3(TOK / 128, DD / 128, 3), 256, 0, stream>>>(
        Xqh, Xql, Xkvh, Xkvl, WTh, WTl, ln1_g, ln1_b, ln2_g, ln2_b, qwb, kwb, vw);

    vtrans_kernel<<<dim3(BB * NH, SS / 64), 256, 0, stream>>>(vw, vtw);

    attn_mfma_kernel<<<dim3(BB * NH, SS / 64), 256, 0, stream>>>(qwb, kwb, vtw, zb);

    oproj_gemm_kernel<<<dim3(TOK / 128, DD / 128), 256, 0, stream>>>(zb, WOTh, WOTl, out);
}

// Round 9
// 230.680 us; speedup vs baseline: 6.3574x; 1.1332x over previous
//
#include <hip/hip_runtime.h>
#include <math.h>
#include <stdint.h>

#define BB 2
#define SS 2048
#define DD 768
#define NH 12
#define HH 64
#define TOK 4096  // BB*SS

typedef __attribute__((ext_vector_type(8))) short bf16x8;
typedef __attribute__((ext_vector_type(4))) float f32x4;

#define AS1 __attribute__((address_space(1)))
#define AS3 __attribute__((address_space(3)))

__device__ __forceinline__ void gload16(const void* g, void* l) {
    __builtin_amdgcn_global_load_lds((AS1 const void*)g, (AS3 void*)l, 16, 0, 0);
}

__device__ __forceinline__ unsigned short f2bf(float f) {  // RNE
    union { float f; uint32_t u; } v; v.f = f;
    uint32_t r = v.u + 0x7fffu + ((v.u >> 16) & 1u);
    return (unsigned short)(r >> 16);
}
__device__ __forceinline__ float bf2f(unsigned short h) {
    union { uint32_t u; float f; } v; v.u = ((uint32_t)h) << 16;
    return v.f;
}

// ---------------------------------------------------------------------------
// Prep A: convert fp32 -> bf16 for both X inputs. grid (n4/256, 2).
// ---------------------------------------------------------------------------
__global__ __launch_bounds__(256) void cvt_kernel(
    const float* __restrict__ a, const float* __restrict__ b,
    unsigned short* __restrict__ oa, unsigned short* __restrict__ ob, int n4)
{
    int i = blockIdx.x * 256 + threadIdx.x;
    if (i >= n4) return;
    const float* src = blockIdx.y ? b : a;
    unsigned short* dst = blockIdx.y ? ob : oa;
    float4 v = ((const float4*)src)[i];
    ushort4 h;
    h.x = f2bf(v.x); h.y = f2bf(v.y); h.z = f2bf(v.z); h.w = f2bf(v.w);
    ((ushort4*)dst)[i] = h;
}

// ---------------------------------------------------------------------------
// Prep B: transpose W_{Q,K,V} (NH,DD,HH fp32) -> WT[which][n*64+h][d] bf16.
// grid (NH, DD/64, 3).
// ---------------------------------------------------------------------------
__global__ __launch_bounds__(256) void wt_kernel(
    const float* __restrict__ W_Q, const float* __restrict__ W_K,
    const float* __restrict__ W_V, unsigned short* __restrict__ WT)
{
    __shared__ float lds[64][65];
    const int n = blockIdx.x;
    const int d0 = blockIdx.y * 64;
    const int which = blockIdx.z;
    const float* W = (which == 0) ? W_Q : (which == 1) ? W_K : W_V;
    unsigned short* T = WT + (size_t)which * DD * DD;
    const int t = threadIdx.x;

    {
        const int dr = t >> 2, h0 = (t & 3) * 16;
        const float* src = W + (size_t)n * DD * HH + (size_t)(d0 + dr) * HH + h0;
        #pragma unroll
        for (int i = 0; i < 4; ++i) {
            float4 v = *(const float4*)(src + i * 4);
            lds[dr][h0 + i * 4 + 0] = v.x;
            lds[dr][h0 + i * 4 + 1] = v.y;
            lds[dr][h0 + i * 4 + 2] = v.z;
            lds[dr][h0 + i * 4 + 3] = v.w;
        }
    }
    __syncthreads();
    {
        const int h = t >> 2, dq = (t & 3) * 16;
        unsigned short th[16];
        #pragma unroll
        for (int i = 0; i < 16; ++i) th[i] = f2bf(lds[dq + i][h]);
        unsigned short* dh = T + (size_t)(n * HH + h) * DD + d0 + dq;
        *(bf16x8*)dh       = *(const bf16x8*)&th[0];
        *(bf16x8*)(dh + 8) = *(const bf16x8*)&th[8];
    }
}

// ---------------------------------------------------------------------------
// Prep D: transpose W_O fp32 [k=768][d=768] -> [d][k] bf16. grid (12, 12).
// ---------------------------------------------------------------------------
__global__ __launch_bounds__(256) void wot_kernel(
    const float* __restrict__ W, unsigned short* __restrict__ Th)
{
    __shared__ float lds[64][65];
    const int k0 = blockIdx.x * 64;
    const int d0 = blockIdx.y * 64;
    const int t = threadIdx.x;
    {
        const int kr = t >> 2, c0 = (t & 3) * 16;
        const float* src = W + (size_t)(k0 + kr) * DD + d0 + c0;
        #pragma unroll
        for (int i = 0; i < 4; ++i) {
            float4 v = *(const float4*)(src + i * 4);
            lds[kr][c0 + i * 4 + 0] = v.x;
            lds[kr][c0 + i * 4 + 1] = v.y;
            lds[kr][c0 + i * 4 + 2] = v.z;
            lds[kr][c0 + i * 4 + 3] = v.w;
        }
    }
    __syncthreads();
    {
        const int dr = t >> 2, kq = (t & 3) * 16;
        unsigned short th[16];
        #pragma unroll
        for (int i = 0; i < 16; ++i) th[i] = f2bf(lds[kq + i][dr]);
        unsigned short* dh = Th + (size_t)(d0 + dr) * DD + k0 + kq;
        *(bf16x8*)dh       = *(const bf16x8*)&th[0];
        *(bf16x8*)(dh + 8) = *(const bf16x8*)&th[8];
    }
}

// ---------------------------------------------------------------------------
// Kernel 1: QKV projection MFMA GEMM + fused LayerNorm (single-bf16, no split).
// Q,K written bf16 [b][n][s][h]; V fp32.
// ---------------------------------------------------------------------------
__global__ __launch_bounds__(256) void qkv_gemm_kernel(
    const unsigned short* __restrict__ Xq, const unsigned short* __restrict__ Xkv,
    const unsigned short* __restrict__ WT,
    const float* __restrict__ ln1_g, const float* __restrict__ ln1_b,
    const float* __restrict__ ln2_g, const float* __restrict__ ln2_b,
    unsigned short* __restrict__ qo, unsigned short* __restrict__ ko,
    float* __restrict__ vo)
{
    __shared__ unsigned short A_lds[128 * 64];
    __shared__ unsigned short B_lds[128 * 64];

    const int tid  = threadIdx.x;
    const int lane = tid & 63;
    const int w    = tid >> 6;
    const int which = blockIdx.z;
    const int tok0 = blockIdx.x * 128;
    const int col0 = blockIdx.y * 128;

    const unsigned short* A = (which == 0) ? Xq : Xkv;
    const unsigned short* B = WT + (size_t)which * DD * DD;
    const bool split = (which < 2);   // = "apply LayerNorm"

    f32x4 acc[4][4] = {};

    const int srow = lane >> 3;
    const int scol = (lane & 7) * 8;

    for (int t = 0; t < 12; ++t) {
        const int kk = t * 64;
        __syncthreads();
        #pragma unroll
        for (int j = 0; j < 4; ++j) {
            const int r = (w * 4 + j) * 8 + srow;
            const int ldso = (w * 4 + j) * 512 + lane * 8;
            gload16(A + (size_t)(tok0 + r) * DD + kk + scol, &A_lds[ldso]);
            gload16(B + (size_t)(col0 + r) * DD + kk + scol, &B_lds[ldso]);
        }
        __syncthreads();

        const int wm = (w >> 1) * 64, wn = (w & 1) * 64;
        #pragma unroll
        for (int kh = 0; kh < 2; ++kh) {
            const int ko_ = kh * 32 + (lane >> 4) * 8;
            bf16x8 a[4], b[4];
            #pragma unroll
            for (int m = 0; m < 4; ++m)
                a[m] = *(const bf16x8*)&A_lds[(wm + m * 16 + (lane & 15)) * 64 + ko_];
            #pragma unroll
            for (int n = 0; n < 4; ++n)
                b[n] = *(const bf16x8*)&B_lds[(wn + n * 16 + (lane & 15)) * 64 + ko_];
            #pragma unroll
            for (int m = 0; m < 4; ++m)
                #pragma unroll
                for (int n = 0; n < 4; ++n)
                    acc[m][n] = __builtin_amdgcn_mfma_f32_16x16x32_bf16(a[m], b[n], acc[m][n], 0, 0, 0);
        }
    }

    const int wm = (w >> 1) * 64, wn = (w & 1);
    const int head = (col0 >> 6) + wn;
    unsigned short* dst16 = (which == 0) ? qo : ko;
    const float* gp = (which == 0) ? ln1_g : ln2_g;
    const float* bp = (which == 0) ? ln1_b : ln2_b;

    float gq[4], bq[4];
    #pragma unroll
    for (int n = 0; n < 4; ++n) {
        const int hcol = n * 16 + (lane & 15);
        gq[n] = split ? gp[hcol] : 1.0f;
        bq[n] = split ? bp[hcol] : 0.0f;
    }

    #pragma unroll
    for (int m = 0; m < 4; ++m) {
        #pragma unroll
        for (int r = 0; r < 4; ++r) {
            float e0 = acc[m][0][r], e1 = acc[m][1][r], e2 = acc[m][2][r], e3 = acc[m][3][r];
            const int token = tok0 + wm + m * 16 + (lane >> 4) * 4 + r;
            const int b = token >> 11, s = token & (SS - 1);
            const size_t off = (((size_t)b * NH + head) * SS + s) * HH + (lane & 15);
            if (split) {
                float sum = e0 + e1 + e2 + e3;
                sum += __shfl_xor(sum, 1); sum += __shfl_xor(sum, 2);
                sum += __shfl_xor(sum, 4); sum += __shfl_xor(sum, 8);
                const float mu = sum * (1.0f / 64.0f);
                float d0 = e0 - mu, d1 = e1 - mu, d2 = e2 - mu, d3 = e3 - mu;
                float ss = d0 * d0 + d1 * d1 + d2 * d2 + d3 * d3;
                ss += __shfl_xor(ss, 1); ss += __shfl_xor(ss, 2);
                ss += __shfl_xor(ss, 4); ss += __shfl_xor(ss, 8);
                const float rstd = rsqrtf(ss * (1.0f / 64.0f) + 1e-5f);
                unsigned short* o = dst16 + off;
                o[0]  = f2bf(d0 * rstd * gq[0] + bq[0]);
                o[16] = f2bf(d1 * rstd * gq[1] + bq[1]);
                o[32] = f2bf(d2 * rstd * gq[2] + bq[2]);
                o[48] = f2bf(d3 * rstd * gq[3] + bq[3]);
            } else {
                float* o = vo + off;
                o[0] = e0; o[16] = e1; o[32] = e2; o[48] = e3;
            }
        }
    }
}

// ---------------------------------------------------------------------------
// Prep C: V transpose, fp32 [b][n][s][h] -> bf16 [b][n][h][s].
// ---------------------------------------------------------------------------
__global__ __launch_bounds__(256) void vtrans_kernel(
    const float* __restrict__ v, unsigned short* __restrict__ vt)
{
    __shared__ float lds[64][65];
    const int bn = blockIdx.x;
    const int s0 = blockIdx.y * 64;
    const int t  = threadIdx.x;

    const float* src = v + ((size_t)bn * SS + s0) * HH;
    {
        const int r = t >> 2, c0 = (t & 3) * 16;
        #pragma unroll
        for (int i = 0; i < 4; ++i) {
            float4 x = *(const float4*)(src + (size_t)r * HH + c0 + i * 4);
            lds[r][c0 + i * 4 + 0] = x.x;
            lds[r][c0 + i * 4 + 1] = x.y;
            lds[r][c0 + i * 4 + 2] = x.z;
            lds[r][c0 + i * 4 + 3] = x.w;
        }
    }
    __syncthreads();
    {
        const int h = t >> 2, k0 = (t & 3) * 16;
        unsigned short u[16];
        #pragma unroll
        for (int i = 0; i < 16; ++i) u[i] = f2bf(lds[k0 + i][h]);
        unsigned short* dst = vt + ((size_t)bn * HH + h) * SS + s0 + k0;
        *(bf16x8*)dst       = *(const bf16x8*)&u[0];
        *(bf16x8*)(dst + 8) = *(const bf16x8*)&u[8];
    }
}

// ---------------------------------------------------------------------------
// Kernel 2: causal flash attention, bf16 MFMA, dbuf LDS, 1 barrier/tile
// (unchanged from round 8 — measured 69 us, passing).
// ---------------------------------------------------------------------------
__global__ __launch_bounds__(256) void attn_mfma_kernel(
    const unsigned short* __restrict__ q, const unsigned short* __restrict__ k,
    const unsigned short* __restrict__ vt, unsigned short* __restrict__ zb)
{
    __shared__ unsigned short Kt[2][64 * 64];   // LDS linear; data pre-swizzled at src
    __shared__ unsigned short Vt[2][64 * 64];
    __shared__ unsigned short Pt[4][16 * 64];   // per-wave P tile, XOR-swizzled

    const int tid  = threadIdx.x;
    const int lane = tid & 63;
    const int w    = tid >> 6;
    const int bn   = blockIdx.x;
    const int b    = bn / NH, n = bn % NH;
    const int qbase = (int)(gridDim.y - 1 - blockIdx.y) * 64;  // heavy-first

    const unsigned short* Q = q + (((size_t)b * NH + n) * SS) * HH;
    const unsigned short* K = k + (((size_t)b * NH + n) * SS) * HH;
    const unsigned short* V = vt + (((size_t)b * NH + n) * HH) * SS;

    bf16x8 aq[2];
    {
        const int qr = qbase + w * 16 + (lane & 15);
        #pragma unroll
        for (int kh = 0; kh < 2; ++kh)
            aq[kh] = *(const bf16x8*)(Q + (size_t)qr * HH + kh * 32 + (lane >> 4) * 8);
    }

    float m[4], l[4];
    f32x4 zacc[4] = {};
    #pragma unroll
    for (int r = 0; r < 4; ++r) { m[r] = -INFINITY; l[r] = 0.f; }

    const int rq = (lane >> 4) * 4;
    const int ntiles = qbase / 64 + 1;

    const int lrow = lane >> 3;
    const int sw8  = 8 * ((lane & 7) ^ lrow);   // pre-swizzled source column
    const int ldst = lane * 8;

    auto stage = [&](int bufi, int t_) {
        const int kv0_ = t_ * 64;
        #pragma unroll
        for (int j = 0; j < 2; ++j) {
            const int i_ = 2 * w + j;
            const int row_ = i_ * 8 + lrow;
            gload16(K + (size_t)(kv0_ + row_) * HH + sw8, &Kt[bufi][i_ * 512 + ldst]);
            gload16(V + (size_t)row_ * SS + kv0_ + sw8,   &Vt[bufi][i_ * 512 + ldst]);
        }
    };

    stage(0, 0);

    for (int t = 0; t < ntiles; ++t) {
        const int cur = t & 1;
        const int kv0 = t * 64;
        const bool diag = (t == ntiles - 1);

        __syncthreads();
        if (t + 1 < ntiles) stage(cur ^ 1, t + 1);

        // ---- QK^T ----
        f32x4 sc[4] = {};
        __builtin_amdgcn_s_setprio(1);
        #pragma unroll
        for (int kh = 0; kh < 2; ++kh) {
            #pragma unroll
            for (int nt = 0; nt < 4; ++nt) {
                const int row = nt * 16 + (lane & 15);
                const int idx = (row * 64 + kh * 32 + (lane >> 4) * 8) ^ ((row & 7) << 3);
                bf16x8 kb = *(const bf16x8*)&Kt[cur][idx];
                sc[nt] = __builtin_amdgcn_mfma_f32_16x16x32_bf16(aq[kh], kb, sc[nt], 0, 0, 0);
            }
        }
        __builtin_amdgcn_s_setprio(0);

        // ---- online softmax ----
        #pragma unroll
        for (int r = 0; r < 4; ++r) {
            float s0 = sc[0][r], s1 = sc[1][r], s2 = sc[2][r], s3 = sc[3][r];
            if (diag) {
                const int qrow = qbase + w * 16 + rq + r;
                const int kvl  = kv0 + (lane & 15);
                s0 = (kvl      <= qrow) ? s0 : -INFINITY;
                s1 = (kvl + 16 <= qrow) ? s1 : -INFINITY;
                s2 = (kvl + 32 <= qrow) ? s2 : -INFINITY;
                s3 = (kvl + 48 <= qrow) ? s3 : -INFINITY;
            }
            float mt = fmaxf(fmaxf(s0, s1), fmaxf(s2, s3));
            mt = fmaxf(mt, __shfl_xor(mt, 1));
            mt = fmaxf(mt, __shfl_xor(mt, 2));
            mt = fmaxf(mt, __shfl_xor(mt, 4));
            mt = fmaxf(mt, __shfl_xor(mt, 8));
            const float mn = fmaxf(m[r], mt);
            const float p0 = __expf(s0 - mn), p1 = __expf(s1 - mn);
            const float p2 = __expf(s2 - mn), p3 = __expf(s3 - mn);
            float ps = p0 + p1 + p2 + p3;
            ps += __shfl_xor(ps, 1);
            ps += __shfl_xor(ps, 2);
            ps += __shfl_xor(ps, 4);
            ps += __shfl_xor(ps, 8);
            const float scl = __expf(m[r] - mn);   // 0 on first tile
            l[r] = l[r] * scl + ps;
            m[r] = mn;
            zacc[0][r] *= scl; zacc[1][r] *= scl;
            zacc[2][r] *= scl; zacc[3][r] *= scl;

            const int ql = rq + r;
            const int kl = lane & 15;
            const int base = ql * 64;
            const int sw = (ql & 7) << 3;
            Pt[w][(base + kl     ) ^ sw] = f2bf(p0);
            Pt[w][(base + kl + 16) ^ sw] = f2bf(p1);
            Pt[w][(base + kl + 32) ^ sw] = f2bf(p2);
            Pt[w][(base + kl + 48) ^ sw] = f2bf(p3);
        }

        // ---- PV ----
        __builtin_amdgcn_s_setprio(1);
        #pragma unroll
        for (int kh = 0; kh < 2; ++kh) {
            const int ql  = lane & 15;
            const int pidx = (ql * 64 + kh * 32 + (lane >> 4) * 8) ^ ((ql & 7) << 3);
            bf16x8 pa = *(const bf16x8*)&Pt[w][pidx];
            #pragma unroll
            for (int nt = 0; nt < 4; ++nt) {
                const int row = nt * 16 + (lane & 15);
                const int idx = (row * 64 + kh * 32 + (lane >> 4) * 8) ^ ((row & 7) << 3);
                bf16x8 vb = *(const bf16x8*)&Vt[cur][idx];
                zacc[nt] = __builtin_amdgcn_mfma_f32_16x16x32_bf16(pa, vb, zacc[nt], 0, 0, 0);
            }
        }
        __builtin_amdgcn_s_setprio(0);
    }

    // ---- epilogue: z as bf16 [tok][n*64+h] ----
    #pragma unroll
    for (int r = 0; r < 4; ++r) {
        const int qrow = qbase + w * 16 + rq + r;
        const float invl = 1.0f / l[r];
        unsigned short* o = zb + (((size_t)b * SS + qrow) * NH + n) * HH + (lane & 15);
        o[0]  = f2bf(zacc[0][r] * invl);
        o[16] = f2bf(zacc[1][r] * invl);
        o[32] = f2bf(zacc[2][r] * invl);
        o[48] = f2bf(zacc[3][r] * invl);
    }
}

// ---------------------------------------------------------------------------
// Kernel 3: output projection as MFMA GEMM (single-bf16 W_O).
// ---------------------------------------------------------------------------
__global__ __launch_bounds__(256) void oproj_gemm_kernel(
    const unsigned short* __restrict__ Zb,
    const unsigned short* __restrict__ WOT, float* __restrict__ out)
{
    __shared__ unsigned short A_lds[128 * 64];
    __shared__ unsigned short B_lds[128 * 64];

    const int tid  = threadIdx.x;
    const int lane = tid & 63;
    const int w    = tid >> 6;
    const int tok0 = blockIdx.x * 128;
    const int col0 = blockIdx.y * 128;

    f32x4 acc[4][4] = {};
    const int srow = lane >> 3;
    const int scol = (lane & 7) * 8;

    for (int t = 0; t < 12; ++t) {
        const int kk = t * 64;
        __syncthreads();
        #pragma unroll
        for (int j = 0; j < 4; ++j) {
            const int r = (w * 4 + j) * 8 + srow;
            const int ldso = (w * 4 + j) * 512 + lane * 8;
            gload16(Zb  + (size_t)(tok0 + r) * DD + kk + scol, &A_lds[ldso]);
            gload16(WOT + (size_t)(col0 + r) * DD + kk + scol, &B_lds[ldso]);
        }
        __syncthreads();

        const int wm = (w >> 1) * 64, wn = (w & 1) * 64;
        #pragma unroll
        for (int kh = 0; kh < 2; ++kh) {
            const int ko_ = kh * 32 + (lane >> 4) * 8;
            bf16x8 a[4], b[4];
            #pragma unroll
            for (int m = 0; m < 4; ++m)
                a[m] = *(const bf16x8*)&A_lds[(wm + m * 16 + (lane & 15)) * 64 + ko_];
            #pragma unroll
            for (int n = 0; n < 4; ++n)
                b[n] = *(const bf16x8*)&B_lds[(wn + n * 16 + (lane & 15)) * 64 + ko_];
            #pragma unroll
            for (int m = 0; m < 4; ++m)
                #pragma unroll
                for (int n = 0; n < 4; ++n)
                    acc[m][n] = __builtin_amdgcn_mfma_f32_16x16x32_bf16(a[m], b[n], acc[m][n], 0, 0, 0);
        }
    }

    const int wm = (w >> 1) * 64, wn = (w & 1) * 64;
    #pragma unroll
    for (int m = 0; m < 4; ++m) {
        #pragma unroll
        for (int r = 0; r < 4; ++r) {
            const int token = tok0 + wm + m * 16 + (lane >> 4) * 4 + r;
            float* o = out + (size_t)token * DD + col0 + wn + (lane & 15);
            o[0]  = acc[m][0][r];
            o[16] = acc[m][1][r];
            o[32] = acc[m][2][r];
            o[48] = acc[m][3][r];
        }
    }
}

// ---------------------------------------------------------------------------
extern "C" void kernel_launch(void* const* d_in, const int* in_sizes, int n_in,
                              void* d_out, int out_size, void* d_ws, size_t ws_size,
                              hipStream_t stream) {
    const float* x_q   = (const float*)d_in[0];
    const float* x_kv  = (const float*)d_in[1];
    // d_in[2] = mask (causal, implicit — unused)
    const float* W_Q   = (const float*)d_in[3];
    const float* W_K   = (const float*)d_in[4];
    const float* W_V   = (const float*)d_in[5];
    const float* W_O   = (const float*)d_in[6];
    const float* ln1_g = (const float*)d_in[7];
    const float* ln1_b = (const float*)d_in[8];
    const float* ln2_g = (const float*)d_in[9];
    const float* ln2_b = (const float*)d_in[10];
    float* out = (float*)d_out;

    const size_t P = (size_t)BB * NH * SS * HH;   // 3,145,728 elems
    char* wsb = (char*)d_ws;
    // bytes: qwb[0,2P) kwb[2P,4P) vw[4P,8P) zb[8P,10P) vtw[10P,12P)
    //        Xq[12P,14P) Xkv[14P,16P) WT[20P,..) WOT after
    unsigned short* qwb = (unsigned short*)wsb;
    unsigned short* kwb = qwb + P;
    float*          vw  = (float*)(wsb + 4 * P);
    unsigned short* zb  = (unsigned short*)(wsb + 8 * P);
    unsigned short* vtw = (unsigned short*)(wsb + 10 * P);
    unsigned short* Xq  = (unsigned short*)(wsb + 12 * P);
    unsigned short* Xkv = Xq + P;
    unsigned short* WT  = (unsigned short*)(wsb + 20 * P);
    unsigned short* WOT = WT + 3 * (size_t)DD * DD;

    const int n4 = (int)(P / 4);
    cvt_kernel<<<dim3((n4 + 255) / 256, 2), 256, 0, stream>>>(x_q, x_kv, Xq, Xkv, n4);
    wt_kernel<<<dim3(NH, DD / 64, 3), 256, 0, stream>>>(W_Q, W_K, W_V, WT);
    wot_kernel<<<dim3(DD / 64, DD / 64), 256, 0, stream>>>(W_O, WOT);

    qkv_gemm_kernel<<<dim3(TOK / 128, DD / 128, 3), 256, 0, stream>>>(
        Xq, Xkv, WT, ln1_g, ln1_b, ln2_g, ln2_b, qwb, kwb, vw);

    vtrans_kernel<<<dim3(BB * NH, SS / 64), 256, 0, stream>>>(vw, vtw);

    attn_mfma_kernel<<<dim3(BB * NH, SS / 64), 256, 0, stream>>>(qwb, kwb, vtw, zb);

    oproj_gemm_kernel<<<dim3(TOK / 128, DD / 128), 256, 0, stream>>>(zb, WOT, out);
}